// Round 8
// baseline (1036.339 us; speedup 1.0000x reference)
//
#include <hip/hip_runtime.h>
#include <math.h>

#define F_FILT   40
#define K_GABOR  401
#define HOP      160
#define T_LEN    160000
#define B_BATCH  8
#define EPS_PCENF 1e-6f
#define EPS_INF   1e-5f

#define THREADS  320
#define NWAVES   5
#define RT       10
#define TILE     3200        // THREADS*RT
#define TPC      10          // payload tiles per block
#define CHUNKS   5           // T_LEN / (TILE*TPC)
#define NPT      20          // pooled outputs per tile
#define NPOOL_BLK 200        // TPC*NPT
#define KT       416         // padded tap count
#define KP       208         // pool-kernel f16 pairs (zero padded)
#define HALOP    200         // halo pairs (400 samples)
#define TILEP    1600        // tile pairs
#define XEP      1824        // x pairs incl. pad (max read 1811)
#define RINGP    1800        // comp ring pairs
#define WLS2     208         // max weight uint2 (tap pairs) staged

typedef _Float16 h2_t __attribute__((ext_vector_type(2)));

__device__ __forceinline__ float fdot2(h2_t a, h2_t b, float c) {
    return __builtin_amdgcn_fdot2(a, b, c, false);
}
__device__ __forceinline__ unsigned pk2(float a, float b) {
    return __builtin_bit_cast(unsigned, __builtin_amdgcn_cvt_pkrtz(a, b));
}
__device__ __forceinline__ h2_t bch(unsigned u) {
    return __builtin_bit_cast(h2_t, u);
}

// acc += w * splat(lo(x)) and acc += w * splat(hi(x)), f16x2 full-rate
#define PKFMA_LO(acc, w, x) \
    asm("v_pk_fma_f16 %0, %1, %2, %0 op_sel:[0,0,0] op_sel_hi:[1,0,1]" \
        : "+v"(acc) : "v"(w), "v"(x))
#define PKFMA_HI(acc, w, x) \
    asm("v_pk_fma_f16 %0, %1, %2, %0 op_sel:[0,1,0] op_sel_hi:[1,1,1]" \
        : "+v"(acc) : "v"(w), "v"(x))

// ---------- setup: per-filter packed (wc,ws) f16 taps + f16 pool kernel ----------
__global__ __launch_bounds__(256) void leaf_weights(
    const float* __restrict__ eta_g, const float* __restrict__ sigma_g,
    const float* __restrict__ bw_g,
    unsigned* __restrict__ wtab, unsigned* __restrict__ pktab)
{
    const int f = blockIdx.x;
    const float eta   = eta_g[f];
    const float sigma = sigma_g[f];
    const float bw    = fminf(fmaxf(bw_g[f], 2.0f / 401.0f), 0.5f);
    const float envc  = 0.3989422804014327f / sigma;
    const float den   = bw * 0.5f * 400.0f;

    for (int k = threadIdx.x; k < KT; k += 256) {
        float wc = 0.f, ws = 0.f;
        if (k < K_GABOR) {
            float t = (float)(k - 200);
            float z = t / sigma;
            float e = envc * expf(-0.5f * z * z);
            float ph = eta * t;
            wc = e * cosf(ph);
            ws = e * sinf(ph);
        }
        wtab[f * KT + k] = pk2(wc, ws);
    }
    for (int i = threadIdx.x; i < KP; i += 256) {
        float pp[2];
        for (int j = 0; j < 2; ++j) {
            int k = 2 * i + j;
            float pv = 0.f;
            if (k < K_GABOR) {
                float tp = (float)(k - 201);
                float d = tp / den;
                pv = expf(-0.5f * d * d);
            }
            pp[j] = pv;
        }
        pktab[f * KP + i] = pk2(pp[0], pp[1]);
    }
}

// ---------- main fused kernel: one block = (b, f, chunk of 10 tiles) ----------
__global__ __launch_bounds__(THREADS) void leaf_main(
    const float* __restrict__ x,
    const float* __restrict__ sigma_g,
    const float* __restrict__ bias_g,
    const float* __restrict__ ema_g,
    const float* __restrict__ alpha_g,
    const float* __restrict__ delta_g,
    const float* __restrict__ root_g,
    const unsigned* __restrict__ wtab,
    const unsigned* __restrict__ pktab,
    float* __restrict__ out)
{
    __shared__ unsigned xEl[XEP];      // x as f16 pairs
    __shared__ unsigned ringl[RINGP];  // comp as f16 pairs
    __shared__ unsigned pkpl[KP];      // pool kernel f16 pairs
    __shared__ uint2    wls2[WLS2];    // gabor taps packed (wc,ws) x2
    __shared__ float pooled[NPOOL_BLK];
    __shared__ float waveV[NWAVES];
    __shared__ float p0Lds;

    const int blk   = blockIdx.x;
    const int f     = blk % F_FILT;               // f fastest: mixes heavy/light
    const int b     = (blk / F_FILT) % B_BATCH;
    const int chunk = blk / (F_FILT * B_BATCH);
    const int bf    = b * F_FILT + f;
    const int tid  = threadIdx.x;
    const int lane = tid & 63;
    const int wave = tid >> 6;

    const float sw    = fminf(fmaxf(ema_g[f], 0.0f), 1.0f);
    const float a     = 1.0f - sw;
    const float alpha = fminf(alpha_g[f], 1.0f);
    const float inv_r = 1.0f / fmaxf(root_g[f], 1.0f);
    const float dlt   = delta_g[f];
    const float dpow  = powf(dlt, inv_r);

    // truncated support: taps |k-200| <= R = 4.5*sigma, 16-aligned start
    const float sigma = sigma_g[f];
    const int R    = min(200, (int)ceilf(4.5f * sigma));
    const int S16  = (200 - R) & ~15;
    const int SP   = S16 >> 1;                    // 8-aligned pair start
    int ni = ((200 + R - S16) >> 4) + 1;          // groups of 16 taps (8 pairs)
    ni = min(ni, (KP - SP) >> 3);

    // init LDS
    for (int i = tid; i < XEP;   i += THREADS) xEl[i] = 0u;
    for (int i = tid; i < RINGP; i += THREADS) ringl[i] = 0u;
    for (int i = tid; i < NPOOL_BLK; i += THREADS) pooled[i] = 0.f;
    if (tid < KP) pkpl[tid] = pktab[f * KP + tid];
    {
        const uint2* wt2 = (const uint2*)(wtab + (size_t)f * KT) + SP;
        for (int i = tid; i < ni * 8; i += THREADS) wls2[i] = wt2[i];
    }

    // scan factors: A1 = a^RT
    const float a2 = a * a, a4 = a2 * a2, a8 = a4 * a4;
    const float A1  = a8 * a2;          // a^10
    const float A2  = A1 * A1, A4 = A2 * A2, A8 = A4 * A4;
    const float A16 = A8 * A8, A32 = A16 * A16, A64 = A32 * A32;
    float Al = 1.0f;
    if (lane & 1)  Al *= A1;
    if (lane & 2)  Al *= A2;
    if (lane & 4)  Al *= A4;
    if (lane & 8)  Al *= A8;
    if (lane & 16) Al *= A16;
    if (lane & 32) Al *= A32;

    const float* xb = x + (size_t)b * T_LEN;
    const int tile0 = chunk * TPC;
    const int itStart = (chunk == 0) ? 0 : -1;    // warm-up tile for chunk>0
    const unsigned P0 = 5u * (unsigned)tid;       // pair base = (tid*RT)/2
    const unsigned PS = P0 + (unsigned)SP;
    float carry = 0.f;                            // EMA state (uniform across block)

    // prefetch first tile
    float2 sv[5];
    {
        const float2* src = (const float2*)(xb + (tile0 + itStart) * TILE);
#pragma unroll
        for (int t = 0; t < 5; ++t) sv[t] = src[tid + 320 * t];
    }

    for (int it = itStart; it < TPC; ++it) {
        // read slide tails (prev-tile state, stable since prev stage/pcen)
        const bool doSlide = (it != itStart);
        unsigned tx = 0u, tr = 0u;
        if (doSlide && tid < HALOP) { tx = xEl[TILEP + tid]; tr = ringl[TILEP + tid]; }
        __syncthreads();                           // all waves done with prev tile
        if (doSlide && tid < HALOP) { xEl[tid] = tx; ringl[tid] = tr; }
#pragma unroll
        for (int t = 0; t < 5; ++t) xEl[HALOP + tid + 320 * t] = pk2(sv[t].x, sv[t].y);
        __syncthreads();                           // stage complete

        // issue next tile's global loads (latency hides under conv)
        {
            const int nT0 = (tile0 + it + 1) * TILE;
            const float2* srcN = (const float2*)(xb + (nT0 < T_LEN ? nT0 : 0));
#pragma unroll
            for (int t = 0; t < 5; ++t) sv[t] = srcN[tid + 320 * t];
        }

        // ---- Gabor conv: v_pk_fma_f16 with op_sel splat, f32 flush per 16 taps ----
        float2 accf[RT];
#pragma unroll
        for (int r = 0; r < RT; ++r) accf[r] = make_float2(0.f, 0.f);
        unsigned E[8];
#pragma unroll
        for (int j = 0; j < 8; ++j) E[j] = xEl[PS + j];

        for (int i8 = 0; i8 < ni; ++i8) {
            unsigned acch[RT];
#pragma unroll
            for (int r = 0; r < RT; ++r) acch[r] = 0u;
#pragma unroll
            for (int u = 0; u < 8; ++u) {
                const int kp = i8 * 8 + u;        // global pair index (rel S16)
                const uint2 wp = wls2[kp];        // (wc,ws) even tap / odd tap
#pragma unroll
                for (int r = 0; r < RT; ++r) {
                    // even tap: slot r>>1, half r&1
                    const unsigned xe = E[(u + (r >> 1)) & 7];
                    if ((r & 1) == 0) { PKFMA_LO(acch[r], wp.x, xe); }
                    else              { PKFMA_HI(acch[r], wp.x, xe); }
                    // odd tap: slot (r+1)>>1, half (r+1)&1
                    const unsigned xo = E[(u + ((r + 1) >> 1)) & 7];
                    if (((r + 1) & 1) == 0) { PKFMA_LO(acch[r], wp.y, xo); }
                    else                    { PKFMA_HI(acch[r], wp.y, xo); }
                }
                E[u] = xEl[PS + kp + 8];
            }
#pragma unroll
            for (int r = 0; r < RT; ++r) {        // f32 flush
                const h2_t hh = bch(acch[r]);
                accf[r].x += (float)hh.x;
                accf[r].y += (float)hh.y;
            }
        }

        // ---- power + thread-local EMA ----
        float p[RT], up[RT];
        float uu = 0.f;
#pragma unroll
        for (int r = 0; r < RT; ++r) {
            p[r] = fmaf(accf[r].x, accf[r].x, accf[r].y * accf[r].y);
            uu = fmaf(a, uu, sw * p[r]);
            up[r] = uu;
        }
        if (chunk == 0 && it == 0 && tid == 0) p0Lds = p[0];

        // ---- EMA: intra-wave Kogge-Stone scan ----
        float v = uu;
        {
            float tv;
            tv = __shfl_up(v, 1);  if (lane >= 1)  v = fmaf(A1,  tv, v);
            tv = __shfl_up(v, 2);  if (lane >= 2)  v = fmaf(A2,  tv, v);
            tv = __shfl_up(v, 4);  if (lane >= 4)  v = fmaf(A4,  tv, v);
            tv = __shfl_up(v, 8);  if (lane >= 8)  v = fmaf(A8,  tv, v);
            tv = __shfl_up(v, 16); if (lane >= 16) v = fmaf(A16, tv, v);
            tv = __shfl_up(v, 32); if (lane >= 32) v = fmaf(A32, tv, v);
        }
        if (lane == 63) waveV[wave] = v;
        __syncthreads();                           // waveV ready (+ p0Lds)

        // all threads redundantly fold wave carries (no serial section)
        float cw, cc = (chunk == 0 && it == 0) ? p0Lds : carry;
#pragma unroll
        for (int w = 0; w < NWAVES; ++w) {
            if (w == wave) cw = cc;
            cc = fmaf(A64, cc, waveV[w]);
        }
        carry = cc;                                // uniform across block
        float cin;
        {
            float ve = __shfl_up(v, 1);
            if (lane == 0) ve = 0.f;
            cin = fmaf(Al, cw, ve);
        }

        // ---- PCEN + f16 ring writes ----
        float apr = a;
#pragma unroll
        for (int j = 0; j < 5; ++j) {
            const float e0 = fmaf(apr, cin, up[2 * j]);     apr *= a;
            const float e1 = fmaf(apr, cin, up[2 * j + 1]); apr *= a;
            const float q0 = fmaf(p[2 * j],     exp2f(-alpha * log2f(EPS_PCENF + e0)), dlt);
            const float q1 = fmaf(p[2 * j + 1], exp2f(-alpha * log2f(EPS_PCENF + e1)), dlt);
            const float c0 = exp2f(inv_r * log2f(q0)) - dpow;
            const float c1 = exp2f(inv_r * log2f(q1)) - dpow;
            ringl[HALOP + P0 + j] = pk2(c0, c1);
        }
        __syncthreads();                           // ring complete

        // ---- pooling via dot2: 20 outputs x 16 lanes ----
        if (it >= 0) {
            const int o = tid >> 4, l = tid & 15;
            float part = 0.f;
#pragma unroll
            for (int t = 0; t < 13; ++t) {
                const int kpp = l + 16 * t;   // 0..207, pkpl zero-padded
                part = fdot2(bch(ringl[o * 80 + kpp]), bch(pkpl[kpp]), part);
            }
            part += __shfl_xor(part, 1, 16);
            part += __shfl_xor(part, 2, 16);
            part += __shfl_xor(part, 4, 16);
            part += __shfl_xor(part, 8, 16);
            if (l == 0) pooled[it * NPT + o] += part;
        }
    }
    __syncthreads();

    const float bias = bias_g[f];
    for (int i = tid; i < NPOOL_BLK; i += THREADS)
        out[(size_t)bf * 1000 + (size_t)(tile0 * NPT) + i] = pooled[i] + bias;
}

// ---------- instance norm over 1000 frames, in place ----------
__global__ __launch_bounds__(256) void leaf_norm(float* __restrict__ out)
{
    const int bf = blockIdx.x;
    float* p = out + (size_t)bf * 1000;
    __shared__ float buf[1000];
    __shared__ float red[4];
    const int tid = threadIdx.x;
    const int lane = tid & 63, wave = tid >> 6;

    float sum = 0.0f;
    for (int i = tid; i < 1000; i += 256) { float v = p[i]; buf[i] = v; sum += v; }
    for (int m = 1; m < 64; m <<= 1) sum += __shfl_xor(sum, m);
    if (lane == 0) red[wave] = sum;
    __syncthreads();
    const float mean = (red[0] + red[1] + red[2] + red[3]) * 0.001f;

    float vs = 0.0f;
    for (int i = tid; i < 1000; i += 256) { float d = buf[i] - mean; vs += d * d; }
    for (int m = 1; m < 64; m <<= 1) vs += __shfl_xor(vs, m);
    __syncthreads();
    if (lane == 0) red[wave] = vs;
    __syncthreads();
    const float var   = (red[0] + red[1] + red[2] + red[3]) * 0.001f;
    const float scale = rsqrtf(var + EPS_INF);
    for (int i = tid; i < 1000; i += 256) p[i] = (buf[i] - mean) * scale;
}

extern "C" void kernel_launch(void* const* d_in, const int* in_sizes, int n_in,
                              void* d_out, int out_size, void* d_ws, size_t ws_size,
                              hipStream_t stream)
{
    const float* x     = (const float*)d_in[0];
    const float* eta   = (const float*)d_in[1];
    const float* sigma = (const float*)d_in[2];
    const float* bw    = (const float*)d_in[3];
    const float* bias  = (const float*)d_in[4];
    const float* emaw  = (const float*)d_in[5];
    const float* alpha = (const float*)d_in[6];
    const float* delta = (const float*)d_in[7];
    const float* root  = (const float*)d_in[8];
    float* outp = (float*)d_out;

    unsigned* wtab  = (unsigned*)d_ws;                                // 40*416*4 B
    unsigned* pktab = (unsigned*)((char*)d_ws + (size_t)F_FILT * KT * sizeof(unsigned));

    hipLaunchKernelGGL(leaf_weights, dim3(F_FILT), dim3(256), 0, stream,
                       eta, sigma, bw, wtab, pktab);
    hipLaunchKernelGGL(leaf_main, dim3(B_BATCH * F_FILT * CHUNKS), dim3(THREADS), 0, stream,
                       x, sigma, bias, emaw, alpha, delta, root, wtab, pktab, outp);
    hipLaunchKernelGGL(leaf_norm, dim3(B_BATCH * F_FILT), dim3(256), 0, stream, outp);
}

// Round 10
// 373.973 us; speedup vs baseline: 2.7712x; 2.7712x over previous
//
#include <hip/hip_runtime.h>
#include <math.h>

#define F_FILT   40
#define K_GABOR  401
#define HOP      160
#define T_LEN    160000
#define B_BATCH  8
#define EPS_PCENF 1e-6f
#define EPS_INF   1e-5f

// ---- kernel1 (MFMA conv) geometry ----
#define NG       5           // filter groups of 8
#define GF       8
#define NKMAX    13          // max K chunks of 32 taps (416)
#define TC       1280        // time samples per block (4 waves x 20 jtiles x 16)
#define UW       20          // j-tiles per wave
#define NCH1     125         // T_LEN / TC
#define OPOFF    852         // odd-phase pair array offset (u32) -- was 740: OVERLAP BUG
#define XPAIRS   (OPOFF + 852)

// ---- kernel2 (PCEN) geometry ----
#define THREADS  320
#define NWAVES   5
#define RT       10
#define TILE     3200
#define TPC      10
#define CHUNKS   5
#define NPT      20
#define NPOOL_BLK 200
#define KP       208
#define HALOP    200
#define TILEP    1600
#define RINGP    1800

typedef _Float16 h2_t  __attribute__((ext_vector_type(2)));
typedef _Float16 half8 __attribute__((ext_vector_type(8)));
typedef float    f32x4 __attribute__((ext_vector_type(4)));

__device__ __forceinline__ float fdot2(h2_t a, h2_t b, float c) {
    return __builtin_amdgcn_fdot2(a, b, c, false);
}
__device__ __forceinline__ unsigned pk2(float a, float b) {
    return __builtin_bit_cast(unsigned, __builtin_amdgcn_cvt_pkrtz(a, b));
}
__device__ __forceinline__ h2_t bch(unsigned u) {
    return __builtin_bit_cast(h2_t, u);
}

// group truncation params (shared formula: leaf_weights & k1)
__device__ __forceinline__ void group_span(float sigma0, int& klo, int& nk) {
    const int R = min(200, (int)ceilf(4.5f * sigma0));
    klo = (200 - R) & ~31;
    nk  = ((200 + R - klo) >> 5) + 1;
    if (nk > NKMAX) nk = NKMAX;
}

// ---------- setup: A-table (16 rows x 416 taps f16 per group) + pool kernel ----------
__global__ __launch_bounds__(256) void leaf_weights(
    const float* __restrict__ eta_g, const float* __restrict__ sigma_g,
    const float* __restrict__ bw_g,
    _Float16* __restrict__ Atab, unsigned* __restrict__ pktab)
{
    const int gi = blockIdx.x;
    const int f0 = gi * GF;
    int klo, nk;
    group_span(sigma_g[f0], klo, nk);

    // A: 52 chunks x 16 rows x 8 taps
    for (int idx = threadIdx.x; idx < 52 * 16 * 8; idx += 256) {
        const int c8 = idx >> 7;
        const int m  = (idx >> 3) & 15;
        const int i  = idx & 7;
        const int f  = f0 + (m >> 1);
        const int k  = klo + c8 * 8 + i;
        float w = 0.f;
        if (k <= 400) {
            const float sg = sigma_g[f];
            const float t  = (float)(k - 200);
            const float z  = t / sg;
            const float e  = (0.3989422804014327f / sg) * expf(-0.5f * z * z);
            const float ph = eta_g[f] * t;
            w = (m & 1) ? e * sinf(ph) : e * cosf(ph);
        }
        Atab[(size_t)(gi * 52 + c8) * 128 + m * 8 + i] = (_Float16)w;
    }
    // pool kernel for this group's 8 filters
    for (int idx = threadIdx.x; idx < GF * KP; idx += 256) {
        const int fl = idx / KP, i = idx % KP;
        const int f = f0 + fl;
        const float bw  = fminf(fmaxf(bw_g[f], 2.0f / 401.0f), 0.5f);
        const float den = bw * 0.5f * 400.0f;
        float pp[2];
        for (int j = 0; j < 2; ++j) {
            int k = 2 * i + j;
            float pv = 0.f;
            if (k < K_GABOR) {
                float tp = (float)(k - 201);
                float d = tp / den;
                pv = expf(-0.5f * d * d);
            }
            pp[j] = pv;
        }
        pktab[f * KP + i] = pk2(pp[0], pp[1]);
    }
}

// ---------- kernel1: MFMA Gabor conv -> power P[f][t] (f16), one batch ----------
__global__ __launch_bounds__(256) void leaf_conv(
    const float* __restrict__ xb,          // x for this batch
    const float* __restrict__ sigma_g,
    const _Float16* __restrict__ Atab,
    _Float16* __restrict__ Pb)             // [40][160000] f16
{
    __shared__ unsigned xpair[XPAIRS];     // even pairs [0,852), odd pairs [852,1704)

    const int gi = blockIdx.x % NG;
    const int ch = blockIdx.x / NG;
    const int f0 = gi * GF;
    const int tid = threadIdx.x;
    const int lane = tid & 63;
    const int w    = tid >> 6;

    int klo, nk;
    group_span(sigma_g[f0], klo, nk);
    const int t0   = ch * TC;
    const int base = t0 + klo - 400;

    // ---- stage x as two phase-shifted f16-pair copies ----
    if (tid < 213) {
        float v[9];
#pragma unroll
        for (int e = 0; e < 9; ++e) {
            const int gidx = base + 8 * tid + e;
            v[e] = (gidx >= 0 && gidx < T_LEN) ? xb[gidx] : 0.f;
        }
        uint4 pe, po;
        pe.x = pk2(v[0], v[1]); pe.y = pk2(v[2], v[3]);
        pe.z = pk2(v[4], v[5]); pe.w = pk2(v[6], v[7]);
        po.x = pk2(v[1], v[2]); po.y = pk2(v[3], v[4]);
        po.z = pk2(v[5], v[6]); po.w = pk2(v[7], v[8]);
        *(uint4*)&xpair[4 * tid]         = pe;
        *(uint4*)&xpair[OPOFF + 4 * tid] = po;
    }
    __syncthreads();

    // ---- k-loop: 20 j-tiles per wave, A persistent-prefetched ----
    const int n  = lane & 15;
    const int kb = lane >> 4;
    const int q0 = ((n + 8 * kb) >> 1) + ((n & 1) ? OPOFF : 0);
    const int pB = q0 + 160 * w;           // + 8u + 16jk

    f32x4 acc[UW];
#pragma unroll
    for (int u = 0; u < UW; ++u) acc[u] = (f32x4){0.f, 0.f, 0.f, 0.f};

    const uint4* Ap = (const uint4*)Atab;
    const int aBase = (gi * 52 + kb) * 16 + n;   // c8 = 4jk + kb
    uint4 aNext = Ap[aBase];
    for (int jk = 0; jk < nk; ++jk) {
        const half8 aCur = __builtin_bit_cast(half8, aNext);
        if (jk + 1 < nk) aNext = Ap[aBase + (jk + 1) * 64];
        const int pJ = pB + 16 * jk;
#pragma unroll
        for (int u = 0; u < UW; ++u) {
            const int p = pJ + 8 * u;
            uint4 bv;
            bv.x = xpair[p];     bv.y = xpair[p + 1];
            bv.z = xpair[p + 2]; bv.w = xpair[p + 3];
            acc[u] = __builtin_amdgcn_mfma_f32_16x16x32_f16(
                aCur, __builtin_bit_cast(half8, bv), acc[u], 0, 0, 0);
        }
    }

    // ---- epilogue: power, store P ----
    const int g  = lane >> 4;
    const int fA = f0 + 2 * g;
#pragma unroll
    for (int u = 0; u < UW; ++u) {
        const int t = t0 + (w * UW + u) * 16 + n;
        const float P0 = acc[u].x * acc[u].x + acc[u].y * acc[u].y;
        const float P1 = acc[u].z * acc[u].z + acc[u].w * acc[u].w;
        Pb[(size_t)fA * T_LEN + t]       = (_Float16)P0;
        Pb[(size_t)(fA + 1) * T_LEN + t] = (_Float16)P1;
    }
}

// ---------- kernel2: EMA + PCEN + pooling for one batch ----------
__global__ __launch_bounds__(THREADS) void leaf_pcen(
    const _Float16* __restrict__ Pb,
    const float* __restrict__ bias_g,
    const float* __restrict__ ema_g,
    const float* __restrict__ alpha_g,
    const float* __restrict__ delta_g,
    const float* __restrict__ root_g,
    const unsigned* __restrict__ pktab,
    float* __restrict__ outB)
{
    __shared__ unsigned ringl[RINGP];
    __shared__ unsigned pkpl[KP];
    __shared__ float pooled[NPOOL_BLK];
    __shared__ float waveV[NWAVES];
    __shared__ float p0Lds;

    const int f     = blockIdx.x % F_FILT;
    const int chunk = blockIdx.x / F_FILT;
    const int tid  = threadIdx.x;
    const int lane = tid & 63;
    const int wave = tid >> 6;

    const float sw    = fminf(fmaxf(ema_g[f], 0.0f), 1.0f);
    const float a     = 1.0f - sw;
    const float alpha = fminf(alpha_g[f], 1.0f);
    const float inv_r = 1.0f / fmaxf(root_g[f], 1.0f);
    const float dlt   = delta_g[f];
    const float dpow  = powf(dlt, inv_r);

    for (int i = tid; i < RINGP; i += THREADS) ringl[i] = 0u;
    for (int i = tid; i < NPOOL_BLK; i += THREADS) pooled[i] = 0.f;
    if (tid < KP) pkpl[tid] = pktab[f * KP + tid];

    const float a2 = a * a, a4 = a2 * a2, a8 = a4 * a4;
    const float A1  = a8 * a2;
    const float A2  = A1 * A1, A4 = A2 * A2, A8 = A4 * A4;
    const float A16 = A8 * A8, A32 = A16 * A16, A64 = A32 * A32;
    float Al = 1.0f;
    if (lane & 1)  Al *= A1;
    if (lane & 2)  Al *= A2;
    if (lane & 4)  Al *= A4;
    if (lane & 8)  Al *= A8;
    if (lane & 16) Al *= A16;
    if (lane & 32) Al *= A32;

    const unsigned* PU = (const unsigned*)(Pb + (size_t)f * T_LEN);
    const int tile0 = chunk * TPC;
    const int itStart = (chunk == 0) ? 0 : -1;
    const unsigned P0 = 5u * (unsigned)tid;
    float carry = 0.f;

    unsigned sv[5];
    {
        const int tb = (tile0 + itStart) * 1600 + tid * 5;
#pragma unroll
        for (int q = 0; q < 5; ++q) sv[q] = PU[tb + q];
    }

    for (int it = itStart; it < TPC; ++it) {
        // unpack powers
        float p[RT];
#pragma unroll
        for (int q = 0; q < 5; ++q) {
            const h2_t hh = bch(sv[q]);
            p[2 * q]     = (float)hh.x;
            p[2 * q + 1] = (float)hh.y;
        }
        // prefetch next tile
        {
            const int nt = tile0 + it + 1;
            const int tb = (nt < CHUNKS * TPC ? nt : 0) * 1600 + tid * 5;
#pragma unroll
            for (int q = 0; q < 5; ++q) sv[q] = PU[tb + q];
        }

        float up[RT];
        float uu = 0.f;
#pragma unroll
        for (int r = 0; r < RT; ++r) {
            uu = fmaf(a, uu, sw * p[r]);
            up[r] = uu;
        }
        if (chunk == 0 && it == 0 && tid == 0) p0Lds = p[0];

        // ring tail (prev tile) read
        const bool doSlide = (it != itStart);
        unsigned tr = 0u;
        if (doSlide && tid < HALOP) tr = ringl[TILEP + tid];

        // intra-wave scan
        float v = uu;
        {
            float tv;
            tv = __shfl_up(v, 1);  if (lane >= 1)  v = fmaf(A1,  tv, v);
            tv = __shfl_up(v, 2);  if (lane >= 2)  v = fmaf(A2,  tv, v);
            tv = __shfl_up(v, 4);  if (lane >= 4)  v = fmaf(A4,  tv, v);
            tv = __shfl_up(v, 8);  if (lane >= 8)  v = fmaf(A8,  tv, v);
            tv = __shfl_up(v, 16); if (lane >= 16) v = fmaf(A16, tv, v);
            tv = __shfl_up(v, 32); if (lane >= 32) v = fmaf(A32, tv, v);
        }
        if (lane == 63) waveV[wave] = v;
        __syncthreads();                      // waveV + prev pooling done

        if (doSlide && tid < HALOP) ringl[tid] = tr;

        float cw, cc = (chunk == 0 && it == 0) ? p0Lds : carry;
#pragma unroll
        for (int ww = 0; ww < NWAVES; ++ww) {
            if (ww == wave) cw = cc;
            cc = fmaf(A64, cc, waveV[ww]);
        }
        carry = cc;
        float cin;
        {
            float ve = __shfl_up(v, 1);
            if (lane == 0) ve = 0.f;
            cin = fmaf(Al, cw, ve);
        }

        float apr = a;
#pragma unroll
        for (int j = 0; j < 5; ++j) {
            const float e0 = fmaf(apr, cin, up[2 * j]);     apr *= a;
            const float e1 = fmaf(apr, cin, up[2 * j + 1]); apr *= a;
            const float q0 = fmaf(p[2 * j],     exp2f(-alpha * log2f(EPS_PCENF + e0)), dlt);
            const float q1 = fmaf(p[2 * j + 1], exp2f(-alpha * log2f(EPS_PCENF + e1)), dlt);
            const float c0 = exp2f(inv_r * log2f(q0)) - dpow;
            const float c1 = exp2f(inv_r * log2f(q1)) - dpow;
            ringl[HALOP + P0 + j] = pk2(c0, c1);
        }
        __syncthreads();                      // ring complete

        if (it >= 0) {
            const int o = tid >> 4, l = tid & 15;
            float part = 0.f;
#pragma unroll
            for (int t = 0; t < 13; ++t) {
                const int kpp = l + 16 * t;
                part = fdot2(bch(ringl[o * 80 + kpp]), bch(pkpl[kpp]), part);
            }
            part += __shfl_xor(part, 1, 16);
            part += __shfl_xor(part, 2, 16);
            part += __shfl_xor(part, 4, 16);
            part += __shfl_xor(part, 8, 16);
            if (l == 0) pooled[it * NPT + o] += part;
        }
    }
    __syncthreads();

    const float bias = bias_g[f];
    for (int i = tid; i < NPOOL_BLK; i += THREADS)
        outB[(size_t)f * 1000 + (size_t)(tile0 * NPT) + i] = pooled[i] + bias;
}

// ---------- instance norm over 1000 frames, in place ----------
__global__ __launch_bounds__(256) void leaf_norm(float* __restrict__ out)
{
    const int bf = blockIdx.x;
    float* p = out + (size_t)bf * 1000;
    __shared__ float buf[1000];
    __shared__ float red[4];
    const int tid = threadIdx.x;
    const int lane = tid & 63, wave = tid >> 6;

    float sum = 0.0f;
    for (int i = tid; i < 1000; i += 256) { float v = p[i]; buf[i] = v; sum += v; }
    for (int m = 1; m < 64; m <<= 1) sum += __shfl_xor(sum, m);
    if (lane == 0) red[wave] = sum;
    __syncthreads();
    const float mean = (red[0] + red[1] + red[2] + red[3]) * 0.001f;

    float vs = 0.0f;
    for (int i = tid; i < 1000; i += 256) { float d = buf[i] - mean; vs += d * d; }
    for (int m = 1; m < 64; m <<= 1) vs += __shfl_xor(vs, m);
    __syncthreads();
    if (lane == 0) red[wave] = vs;
    __syncthreads();
    const float var   = (red[0] + red[1] + red[2] + red[3]) * 0.001f;
    const float scale = rsqrtf(var + EPS_INF);
    for (int i = tid; i < 1000; i += 256) p[i] = (buf[i] - mean) * scale;
}

extern "C" void kernel_launch(void* const* d_in, const int* in_sizes, int n_in,
                              void* d_out, int out_size, void* d_ws, size_t ws_size,
                              hipStream_t stream)
{
    const float* x     = (const float*)d_in[0];
    const float* eta   = (const float*)d_in[1];
    const float* sigma = (const float*)d_in[2];
    const float* bw    = (const float*)d_in[3];
    const float* bias  = (const float*)d_in[4];
    const float* emaw  = (const float*)d_in[5];
    const float* alpha = (const float*)d_in[6];
    const float* delta = (const float*)d_in[7];
    const float* root  = (const float*)d_in[8];
    float* outp = (float*)d_out;

    _Float16* Atab  = (_Float16*)d_ws;                       // 5*52*128 halfs = 133,120 B
    unsigned* pktab = (unsigned*)((char*)d_ws + 133120);     // 33,280 B
    _Float16* Pb    = (_Float16*)((char*)d_ws + 166400);     // 40*160000*2 = 12.8 MB

    hipLaunchKernelGGL(leaf_weights, dim3(NG), dim3(256), 0, stream,
                       eta, sigma, bw, Atab, pktab);
    for (int b = 0; b < B_BATCH; ++b) {
        hipLaunchKernelGGL(leaf_conv, dim3(NG * NCH1), dim3(256), 0, stream,
                           x + (size_t)b * T_LEN, sigma, Atab, Pb);
        hipLaunchKernelGGL(leaf_pcen, dim3(F_FILT * CHUNKS), dim3(THREADS), 0, stream,
                           Pb, bias, emaw, alpha, delta, root, pktab,
                           outp + (size_t)b * F_FILT * 1000);
    }
    hipLaunchKernelGGL(leaf_norm, dim3(B_BATCH * F_FILT), dim3(256), 0, stream, outp);
}

// Round 11
// 186.778 us; speedup vs baseline: 5.5485x; 2.0022x over previous
//
#include <hip/hip_runtime.h>
#include <math.h>

#define F_FILT   40
#define K_GABOR  401
#define HOP      160
#define T_LEN    160000
#define B_BATCH  8
#define EPS_PCENF 1e-6f
#define EPS_INF   1e-5f

// ---- kernel1 (MFMA conv) geometry ----
#define NG       5           // filter groups of 8
#define GF       8
#define NKMAX    13          // max K chunks of 32 taps (416)
#define TC       1280        // time samples per block (4 waves x 20 jtiles x 16)
#define UW       20          // j-tiles per wave
#define NCH1     125         // T_LEN / TC
#define OPOFF    852         // odd-phase pair array offset (u32)
#define XPAIRS   (OPOFF + 852)

// ---- kernel2 (PCEN) geometry ----
#define THREADS  320
#define NWAVES   5
#define RT       10
#define TILE     3200
#define TPC      10
#define CHUNKS   5
#define NPT      20
#define NPOOL_BLK 200
#define KP       208
#define HALOP    200
#define TILEP    1600
#define RINGP    1800

typedef _Float16 h2_t  __attribute__((ext_vector_type(2)));
typedef _Float16 half8 __attribute__((ext_vector_type(8)));
typedef float    f32x4 __attribute__((ext_vector_type(4)));

__device__ __forceinline__ float fdot2(h2_t a, h2_t b, float c) {
    return __builtin_amdgcn_fdot2(a, b, c, false);
}
__device__ __forceinline__ unsigned pk2(float a, float b) {
    return __builtin_bit_cast(unsigned, __builtin_amdgcn_cvt_pkrtz(a, b));
}
__device__ __forceinline__ h2_t bch(unsigned u) {
    return __builtin_bit_cast(h2_t, u);
}

// group truncation params (shared formula: leaf_weights & k1)
__device__ __forceinline__ void group_span(float sigma0, int& klo, int& nk) {
    const int R = min(200, (int)ceilf(4.5f * sigma0));
    klo = (200 - R) & ~31;
    nk  = ((200 + R - klo) >> 5) + 1;
    if (nk > NKMAX) nk = NKMAX;
}

// ---------- setup: A-table (16 rows x 416 taps f16 per group) + pool kernel ----------
__global__ __launch_bounds__(256) void leaf_weights(
    const float* __restrict__ eta_g, const float* __restrict__ sigma_g,
    const float* __restrict__ bw_g,
    _Float16* __restrict__ Atab, unsigned* __restrict__ pktab)
{
    const int gi = blockIdx.x;
    const int f0 = gi * GF;
    int klo, nk;
    group_span(sigma_g[f0], klo, nk);

    // A: 52 chunks x 16 rows x 8 taps
    for (int idx = threadIdx.x; idx < 52 * 16 * 8; idx += 256) {
        const int c8 = idx >> 7;
        const int m  = (idx >> 3) & 15;
        const int i  = idx & 7;
        const int f  = f0 + (m >> 1);
        const int k  = klo + c8 * 8 + i;
        float w = 0.f;
        if (k <= 400) {
            const float sg = sigma_g[f];
            const float t  = (float)(k - 200);
            const float z  = t / sg;
            const float e  = (0.3989422804014327f / sg) * expf(-0.5f * z * z);
            const float ph = eta_g[f] * t;
            w = (m & 1) ? e * sinf(ph) : e * cosf(ph);
        }
        Atab[(size_t)(gi * 52 + c8) * 128 + m * 8 + i] = (_Float16)w;
    }
    // pool kernel for this group's 8 filters
    for (int idx = threadIdx.x; idx < GF * KP; idx += 256) {
        const int fl = idx / KP, i = idx % KP;
        const int f = f0 + fl;
        const float bw  = fminf(fmaxf(bw_g[f], 2.0f / 401.0f), 0.5f);
        const float den = bw * 0.5f * 400.0f;
        float pp[2];
        for (int j = 0; j < 2; ++j) {
            int k = 2 * i + j;
            float pv = 0.f;
            if (k < K_GABOR) {
                float tp = (float)(k - 201);
                float d = tp / den;
                pv = expf(-0.5f * d * d);
            }
            pp[j] = pv;
        }
        pktab[f * KP + i] = pk2(pp[0], pp[1]);
    }
}

// ---------- kernel1: MFMA Gabor conv -> power P[b][f][t] (f16), ALL batches ----------
__global__ __launch_bounds__(256) void leaf_conv(
    const float* __restrict__ x,
    const float* __restrict__ sigma_g,
    const _Float16* __restrict__ Atab,
    _Float16* __restrict__ Pall)           // [8][40][160000] f16
{
    __shared__ unsigned xpair[XPAIRS];     // even pairs [0,852), odd pairs [852,1704)

    const int gi = blockIdx.x % NG;
    const int ch = (blockIdx.x / NG) % NCH1;
    const int b  = blockIdx.x / (NG * NCH1);
    const int f0 = gi * GF;
    const int tid = threadIdx.x;
    const int lane = tid & 63;
    const int w    = tid >> 6;

    const float* __restrict__ xb = x + (size_t)b * T_LEN;
    _Float16* __restrict__ Pb = Pall + (size_t)b * F_FILT * T_LEN;

    int klo, nk;
    group_span(sigma_g[f0], klo, nk);
    const int t0   = ch * TC;
    const int base = t0 + klo - 400;

    // ---- stage x as two phase-shifted f16-pair copies ----
    if (tid < 213) {
        float v[9];
#pragma unroll
        for (int e = 0; e < 9; ++e) {
            const int gidx = base + 8 * tid + e;
            v[e] = (gidx >= 0 && gidx < T_LEN) ? xb[gidx] : 0.f;
        }
        uint4 pe, po;
        pe.x = pk2(v[0], v[1]); pe.y = pk2(v[2], v[3]);
        pe.z = pk2(v[4], v[5]); pe.w = pk2(v[6], v[7]);
        po.x = pk2(v[1], v[2]); po.y = pk2(v[3], v[4]);
        po.z = pk2(v[5], v[6]); po.w = pk2(v[7], v[8]);
        *(uint4*)&xpair[4 * tid]         = pe;
        *(uint4*)&xpair[OPOFF + 4 * tid] = po;
    }
    __syncthreads();

    // ---- k-loop: 20 j-tiles per wave, A persistent-prefetched ----
    const int n  = lane & 15;
    const int kb = lane >> 4;
    const int q0 = ((n + 8 * kb) >> 1) + ((n & 1) ? OPOFF : 0);
    const int pB = q0 + 160 * w;           // + 8u + 16jk

    f32x4 acc[UW];
#pragma unroll
    for (int u = 0; u < UW; ++u) acc[u] = (f32x4){0.f, 0.f, 0.f, 0.f};

    const uint4* Ap = (const uint4*)Atab;
    const int aBase = (gi * 52 + kb) * 16 + n;   // c8 = 4jk + kb
    uint4 aNext = Ap[aBase];
    for (int jk = 0; jk < nk; ++jk) {
        const half8 aCur = __builtin_bit_cast(half8, aNext);
        if (jk + 1 < nk) aNext = Ap[aBase + (jk + 1) * 64];
        const int pJ = pB + 16 * jk;
#pragma unroll
        for (int u = 0; u < UW; ++u) {
            const int p = pJ + 8 * u;
            uint4 bv;
            bv.x = xpair[p];     bv.y = xpair[p + 1];
            bv.z = xpair[p + 2]; bv.w = xpair[p + 3];
            acc[u] = __builtin_amdgcn_mfma_f32_16x16x32_f16(
                aCur, __builtin_bit_cast(half8, bv), acc[u], 0, 0, 0);
        }
    }

    // ---- epilogue: power, store P ----
    const int g  = lane >> 4;
    const int fA = f0 + 2 * g;
#pragma unroll
    for (int u = 0; u < UW; ++u) {
        const int t = t0 + (w * UW + u) * 16 + n;
        const float P0 = acc[u].x * acc[u].x + acc[u].y * acc[u].y;
        const float P1 = acc[u].z * acc[u].z + acc[u].w * acc[u].w;
        Pb[(size_t)fA * T_LEN + t]       = (_Float16)P0;
        Pb[(size_t)(fA + 1) * T_LEN + t] = (_Float16)P1;
    }
}

// ---------- kernel2: EMA + PCEN + pooling, ALL batches ----------
__global__ __launch_bounds__(THREADS) void leaf_pcen(
    const _Float16* __restrict__ Pall,
    const float* __restrict__ bias_g,
    const float* __restrict__ ema_g,
    const float* __restrict__ alpha_g,
    const float* __restrict__ delta_g,
    const float* __restrict__ root_g,
    const unsigned* __restrict__ pktab,
    float* __restrict__ outp)
{
    __shared__ unsigned ringl[RINGP];
    __shared__ unsigned pkpl[KP];
    __shared__ float pooled[NPOOL_BLK];
    __shared__ float waveV[NWAVES];
    __shared__ float p0Lds;

    const int f     = blockIdx.x % F_FILT;
    const int chunk = (blockIdx.x / F_FILT) % CHUNKS;
    const int b     = blockIdx.x / (F_FILT * CHUNKS);
    const int tid  = threadIdx.x;
    const int lane = tid & 63;
    const int wave = tid >> 6;

    const float sw    = fminf(fmaxf(ema_g[f], 0.0f), 1.0f);
    const float a     = 1.0f - sw;
    const float alpha = fminf(alpha_g[f], 1.0f);
    const float inv_r = 1.0f / fmaxf(root_g[f], 1.0f);
    const float dlt   = delta_g[f];
    const float dpow  = powf(dlt, inv_r);

    for (int i = tid; i < RINGP; i += THREADS) ringl[i] = 0u;
    for (int i = tid; i < NPOOL_BLK; i += THREADS) pooled[i] = 0.f;
    if (tid < KP) pkpl[tid] = pktab[f * KP + tid];

    const float a2 = a * a, a4 = a2 * a2, a8 = a4 * a4;
    const float A1  = a8 * a2;
    const float A2  = A1 * A1, A4 = A2 * A2, A8 = A4 * A4;
    const float A16 = A8 * A8, A32 = A16 * A16, A64 = A32 * A32;
    float Al = 1.0f;
    if (lane & 1)  Al *= A1;
    if (lane & 2)  Al *= A2;
    if (lane & 4)  Al *= A4;
    if (lane & 8)  Al *= A8;
    if (lane & 16) Al *= A16;
    if (lane & 32) Al *= A32;

    const unsigned* PU = (const unsigned*)(Pall + ((size_t)b * F_FILT + f) * T_LEN);
    const int tile0 = chunk * TPC;
    const int itStart = (chunk == 0) ? 0 : -1;
    const unsigned P0 = 5u * (unsigned)tid;
    float carry = 0.f;

    unsigned sv[5];
    {
        const int tb = (tile0 + itStart) * 1600 + tid * 5;
#pragma unroll
        for (int q = 0; q < 5; ++q) sv[q] = PU[tb + q];
    }

    for (int it = itStart; it < TPC; ++it) {
        // unpack powers
        float p[RT];
#pragma unroll
        for (int q = 0; q < 5; ++q) {
            const h2_t hh = bch(sv[q]);
            p[2 * q]     = (float)hh.x;
            p[2 * q + 1] = (float)hh.y;
        }
        // prefetch next tile
        {
            const int nt = tile0 + it + 1;
            const int tb = (nt < CHUNKS * TPC ? nt : 0) * 1600 + tid * 5;
#pragma unroll
            for (int q = 0; q < 5; ++q) sv[q] = PU[tb + q];
        }

        float up[RT];
        float uu = 0.f;
#pragma unroll
        for (int r = 0; r < RT; ++r) {
            uu = fmaf(a, uu, sw * p[r]);
            up[r] = uu;
        }
        if (chunk == 0 && it == 0 && tid == 0) p0Lds = p[0];

        // ring tail (prev tile) read
        const bool doSlide = (it != itStart);
        unsigned tr = 0u;
        if (doSlide && tid < HALOP) tr = ringl[TILEP + tid];

        // intra-wave scan
        float v = uu;
        {
            float tv;
            tv = __shfl_up(v, 1);  if (lane >= 1)  v = fmaf(A1,  tv, v);
            tv = __shfl_up(v, 2);  if (lane >= 2)  v = fmaf(A2,  tv, v);
            tv = __shfl_up(v, 4);  if (lane >= 4)  v = fmaf(A4,  tv, v);
            tv = __shfl_up(v, 8);  if (lane >= 8)  v = fmaf(A8,  tv, v);
            tv = __shfl_up(v, 16); if (lane >= 16) v = fmaf(A16, tv, v);
            tv = __shfl_up(v, 32); if (lane >= 32) v = fmaf(A32, tv, v);
        }
        if (lane == 63) waveV[wave] = v;
        __syncthreads();                      // waveV + prev pooling done

        if (doSlide && tid < HALOP) ringl[tid] = tr;

        float cw, cc = (chunk == 0 && it == 0) ? p0Lds : carry;
#pragma unroll
        for (int ww = 0; ww < NWAVES; ++ww) {
            if (ww == wave) cw = cc;
            cc = fmaf(A64, cc, waveV[ww]);
        }
        carry = cc;
        float cin;
        {
            float ve = __shfl_up(v, 1);
            if (lane == 0) ve = 0.f;
            cin = fmaf(Al, cw, ve);
        }

        float apr = a;
#pragma unroll
        for (int j = 0; j < 5; ++j) {
            const float e0 = fmaf(apr, cin, up[2 * j]);     apr *= a;
            const float e1 = fmaf(apr, cin, up[2 * j + 1]); apr *= a;
            const float q0 = fmaf(p[2 * j],     exp2f(-alpha * log2f(EPS_PCENF + e0)), dlt);
            const float q1 = fmaf(p[2 * j + 1], exp2f(-alpha * log2f(EPS_PCENF + e1)), dlt);
            const float c0 = exp2f(inv_r * log2f(q0)) - dpow;
            const float c1 = exp2f(inv_r * log2f(q1)) - dpow;
            ringl[HALOP + P0 + j] = pk2(c0, c1);
        }
        __syncthreads();                      // ring complete

        if (it >= 0) {
            const int o = tid >> 4, l = tid & 15;
            float part = 0.f;
#pragma unroll
            for (int t = 0; t < 13; ++t) {
                const int kpp = l + 16 * t;
                part = fdot2(bch(ringl[o * 80 + kpp]), bch(pkpl[kpp]), part);
            }
            part += __shfl_xor(part, 1, 16);
            part += __shfl_xor(part, 2, 16);
            part += __shfl_xor(part, 4, 16);
            part += __shfl_xor(part, 8, 16);
            if (l == 0) pooled[it * NPT + o] += part;
        }
    }
    __syncthreads();

    const float bias = bias_g[f];
    for (int i = tid; i < NPOOL_BLK; i += THREADS)
        outp[((size_t)b * F_FILT + f) * 1000 + (size_t)(tile0 * NPT) + i] = pooled[i] + bias;
}

// ---------- instance norm over 1000 frames, in place ----------
__global__ __launch_bounds__(256) void leaf_norm(float* __restrict__ out)
{
    const int bf = blockIdx.x;
    float* p = out + (size_t)bf * 1000;
    __shared__ float buf[1000];
    __shared__ float red[4];
    const int tid = threadIdx.x;
    const int lane = tid & 63, wave = tid >> 6;

    float sum = 0.0f;
    for (int i = tid; i < 1000; i += 256) { float v = p[i]; buf[i] = v; sum += v; }
    for (int m = 1; m < 64; m <<= 1) sum += __shfl_xor(sum, m);
    if (lane == 0) red[wave] = sum;
    __syncthreads();
    const float mean = (red[0] + red[1] + red[2] + red[3]) * 0.001f;

    float vs = 0.0f;
    for (int i = tid; i < 1000; i += 256) { float d = buf[i] - mean; vs += d * d; }
    for (int m = 1; m < 64; m <<= 1) vs += __shfl_xor(vs, m);
    __syncthreads();
    if (lane == 0) red[wave] = vs;
    __syncthreads();
    const float var   = (red[0] + red[1] + red[2] + red[3]) * 0.001f;
    const float scale = rsqrtf(var + EPS_INF);
    for (int i = tid; i < 1000; i += 256) p[i] = (buf[i] - mean) * scale;
}

extern "C" void kernel_launch(void* const* d_in, const int* in_sizes, int n_in,
                              void* d_out, int out_size, void* d_ws, size_t ws_size,
                              hipStream_t stream)
{
    const float* x     = (const float*)d_in[0];
    const float* eta   = (const float*)d_in[1];
    const float* sigma = (const float*)d_in[2];
    const float* bw    = (const float*)d_in[3];
    const float* bias  = (const float*)d_in[4];
    const float* emaw  = (const float*)d_in[5];
    const float* alpha = (const float*)d_in[6];
    const float* delta = (const float*)d_in[7];
    const float* root  = (const float*)d_in[8];
    float* outp = (float*)d_out;

    _Float16* Atab  = (_Float16*)d_ws;                       // 133,120 B
    unsigned* pktab = (unsigned*)((char*)d_ws + 133120);     // 33,280 B
    _Float16* Pall  = (_Float16*)((char*)d_ws + 166400);     // 8*40*160000*2 = 102.4 MB

    hipLaunchKernelGGL(leaf_weights, dim3(NG), dim3(256), 0, stream,
                       eta, sigma, bw, Atab, pktab);
    hipLaunchKernelGGL(leaf_conv, dim3(B_BATCH * NG * NCH1), dim3(256), 0, stream,
                       x, sigma, Atab, Pall);
    hipLaunchKernelGGL(leaf_pcen, dim3(B_BATCH * F_FILT * CHUNKS), dim3(THREADS), 0, stream,
                       Pall, bias, emaw, alpha, delta, root, pktab, outp);
    hipLaunchKernelGGL(leaf_norm, dim3(B_BATCH * F_FILT), dim3(256), 0, stream, outp);
}

// Round 12
// 152.227 us; speedup vs baseline: 6.8078x; 1.2270x over previous
//
#include <hip/hip_runtime.h>
#include <math.h>

#define F_FILT   40
#define K_GABOR  401
#define HOP      160
#define T_LEN    160000
#define B_BATCH  8
#define EPS_PCENF 1e-6f
#define EPS_INF   1e-5f

// ---- kernel1 (MFMA conv) geometry ----
#define NG       5           // filter groups of 8
#define GF       8
#define NKMAX    13          // max K chunks of 32 taps (416)
#define TC       1280        // time samples per block (4 waves x 20 jtiles x 16)
#define UW       20          // j-tiles per wave
#define NCH1     125         // T_LEN / TC
#define OPOFF    852         // odd-phase pair array offset (u32)
#define XPAIRS   (OPOFF + 852)

// ---- kernel2 (PCEN) geometry ----
#define THREADS  320
#define NWAVES   5
#define RT       10
#define TILE     3200
#define TPC      10
#define CHUNKS   5
#define NPT      20
#define NPOOL_BLK 200
#define KP       208
#define HALOP    200
#define TILEP    1600
#define RINGP    1800

typedef _Float16 h2_t  __attribute__((ext_vector_type(2)));
typedef _Float16 half8 __attribute__((ext_vector_type(8)));
typedef float    f32x4 __attribute__((ext_vector_type(4)));

__device__ __forceinline__ float fdot2(h2_t a, h2_t b, float c) {
    return __builtin_amdgcn_fdot2(a, b, c, false);
}
__device__ __forceinline__ unsigned pk2(float a, float b) {
    return __builtin_bit_cast(unsigned, __builtin_amdgcn_cvt_pkrtz(a, b));
}
__device__ __forceinline__ h2_t bch(unsigned u) {
    return __builtin_bit_cast(h2_t, u);
}
// hardware transcendentals: v_exp_f32 (2^x), v_log_f32 (log2 x), ~1 ULP
__device__ __forceinline__ float fexp2(float x) { return __builtin_amdgcn_exp2f(x); }
__device__ __forceinline__ float flog2(float x) { return __builtin_amdgcn_logf(x); }

// group truncation params (shared formula: leaf_weights & k1)
__device__ __forceinline__ void group_span(float sigma0, int& klo, int& nk) {
    const int R = min(200, (int)ceilf(4.5f * sigma0));
    klo = (200 - R) & ~31;
    nk  = ((200 + R - klo) >> 5) + 1;
    if (nk > NKMAX) nk = NKMAX;
}

// ---------- setup: A-table (16 rows x 416 taps f16 per group) + pool kernel ----------
__global__ __launch_bounds__(256) void leaf_weights(
    const float* __restrict__ eta_g, const float* __restrict__ sigma_g,
    const float* __restrict__ bw_g,
    _Float16* __restrict__ Atab, unsigned* __restrict__ pktab)
{
    const int gi = blockIdx.x;
    const int f0 = gi * GF;
    int klo, nk;
    group_span(sigma_g[f0], klo, nk);

    // A: 52 chunks x 16 rows x 8 taps
    for (int idx = threadIdx.x; idx < 52 * 16 * 8; idx += 256) {
        const int c8 = idx >> 7;
        const int m  = (idx >> 3) & 15;
        const int i  = idx & 7;
        const int f  = f0 + (m >> 1);
        const int k  = klo + c8 * 8 + i;
        float w = 0.f;
        if (k <= 400) {
            const float sg = sigma_g[f];
            const float t  = (float)(k - 200);
            const float z  = t / sg;
            const float e  = (0.3989422804014327f / sg) * expf(-0.5f * z * z);
            const float ph = eta_g[f] * t;
            w = (m & 1) ? e * sinf(ph) : e * cosf(ph);
        }
        Atab[(size_t)(gi * 52 + c8) * 128 + m * 8 + i] = (_Float16)w;
    }
    // pool kernel for this group's 8 filters
    for (int idx = threadIdx.x; idx < GF * KP; idx += 256) {
        const int fl = idx / KP, i = idx % KP;
        const int f = f0 + fl;
        const float bw  = fminf(fmaxf(bw_g[f], 2.0f / 401.0f), 0.5f);
        const float den = bw * 0.5f * 400.0f;
        float pp[2];
        for (int j = 0; j < 2; ++j) {
            int k = 2 * i + j;
            float pv = 0.f;
            if (k < K_GABOR) {
                float tp = (float)(k - 201);
                float d = tp / den;
                pv = expf(-0.5f * d * d);
            }
            pp[j] = pv;
        }
        pktab[f * KP + i] = pk2(pp[0], pp[1]);
    }
}

// ---------- kernel1: MFMA Gabor conv -> power P[b][f][t] (f16), ALL batches ----------
__global__ __launch_bounds__(256) void leaf_conv(
    const float* __restrict__ x,
    const float* __restrict__ sigma_g,
    const _Float16* __restrict__ Atab,
    _Float16* __restrict__ Pall)           // [8][40][160000] f16
{
    __shared__ unsigned xpair[XPAIRS];     // even pairs [0,852), odd pairs [852,1704)

    const int gi = blockIdx.x % NG;
    const int ch = (blockIdx.x / NG) % NCH1;
    const int b  = blockIdx.x / (NG * NCH1);
    const int f0 = gi * GF;
    const int tid = threadIdx.x;
    const int lane = tid & 63;
    const int w    = tid >> 6;

    const float* __restrict__ xb = x + (size_t)b * T_LEN;
    _Float16* __restrict__ Pb = Pall + (size_t)b * F_FILT * T_LEN;

    int klo, nk;
    group_span(sigma_g[f0], klo, nk);
    const int t0   = ch * TC;
    const int base = t0 + klo - 400;

    // ---- stage x as two phase-shifted f16-pair copies ----
    if (tid < 213) {
        float v[9];
#pragma unroll
        for (int e = 0; e < 9; ++e) {
            const int gidx = base + 8 * tid + e;
            v[e] = (gidx >= 0 && gidx < T_LEN) ? xb[gidx] : 0.f;
        }
        uint4 pe, po;
        pe.x = pk2(v[0], v[1]); pe.y = pk2(v[2], v[3]);
        pe.z = pk2(v[4], v[5]); pe.w = pk2(v[6], v[7]);
        po.x = pk2(v[1], v[2]); po.y = pk2(v[3], v[4]);
        po.z = pk2(v[5], v[6]); po.w = pk2(v[7], v[8]);
        *(uint4*)&xpair[4 * tid]         = pe;
        *(uint4*)&xpair[OPOFF + 4 * tid] = po;
    }
    __syncthreads();

    // ---- k-loop: 20 j-tiles per wave, A persistent-prefetched ----
    const int n  = lane & 15;
    const int kb = lane >> 4;
    const int q0 = ((n + 8 * kb) >> 1) + ((n & 1) ? OPOFF : 0);
    const int pB = q0 + 160 * w;           // + 8u + 16jk

    f32x4 acc[UW];
#pragma unroll
    for (int u = 0; u < UW; ++u) acc[u] = (f32x4){0.f, 0.f, 0.f, 0.f};

    const uint4* Ap = (const uint4*)Atab;
    const int aBase = (gi * 52 + kb) * 16 + n;   // c8 = 4jk + kb
    uint4 aNext = Ap[aBase];
    for (int jk = 0; jk < nk; ++jk) {
        const half8 aCur = __builtin_bit_cast(half8, aNext);
        if (jk + 1 < nk) aNext = Ap[aBase + (jk + 1) * 64];
        const int pJ = pB + 16 * jk;
#pragma unroll
        for (int u = 0; u < UW; ++u) {
            const int p = pJ + 8 * u;
            uint4 bv;
            bv.x = xpair[p];     bv.y = xpair[p + 1];
            bv.z = xpair[p + 2]; bv.w = xpair[p + 3];
            acc[u] = __builtin_amdgcn_mfma_f32_16x16x32_f16(
                aCur, __builtin_bit_cast(half8, bv), acc[u], 0, 0, 0);
        }
    }

    // ---- epilogue: power, store P ----
    const int g  = lane >> 4;
    const int fA = f0 + 2 * g;
#pragma unroll
    for (int u = 0; u < UW; ++u) {
        const int t = t0 + (w * UW + u) * 16 + n;
        const float P0 = acc[u].x * acc[u].x + acc[u].y * acc[u].y;
        const float P1 = acc[u].z * acc[u].z + acc[u].w * acc[u].w;
        Pb[(size_t)fA * T_LEN + t]       = (_Float16)P0;
        Pb[(size_t)(fA + 1) * T_LEN + t] = (_Float16)P1;
    }
}

// ---------- kernel2: EMA + PCEN + pooling, ALL batches ----------
__global__ __launch_bounds__(THREADS) void leaf_pcen(
    const _Float16* __restrict__ Pall,
    const float* __restrict__ bias_g,
    const float* __restrict__ ema_g,
    const float* __restrict__ alpha_g,
    const float* __restrict__ delta_g,
    const float* __restrict__ root_g,
    const unsigned* __restrict__ pktab,
    float* __restrict__ outp)
{
    __shared__ unsigned ringl[RINGP];
    __shared__ unsigned pkpl[KP];
    __shared__ float pooled[NPOOL_BLK];
    __shared__ float waveV[NWAVES];
    __shared__ float p0Lds;

    const int f     = blockIdx.x % F_FILT;
    const int chunk = (blockIdx.x / F_FILT) % CHUNKS;
    const int b     = blockIdx.x / (F_FILT * CHUNKS);
    const int tid  = threadIdx.x;
    const int lane = tid & 63;
    const int wave = tid >> 6;

    const float sw    = fminf(fmaxf(ema_g[f], 0.0f), 1.0f);
    const float a     = 1.0f - sw;
    const float alpha = fminf(alpha_g[f], 1.0f);
    const float inv_r = 1.0f / fmaxf(root_g[f], 1.0f);
    const float dlt   = delta_g[f];
    const float dpow  = fexp2(inv_r * flog2(dlt));

    for (int i = tid; i < RINGP; i += THREADS) ringl[i] = 0u;
    for (int i = tid; i < NPOOL_BLK; i += THREADS) pooled[i] = 0.f;
    if (tid < KP) pkpl[tid] = pktab[f * KP + tid];

    const float a2 = a * a, a4 = a2 * a2, a8 = a4 * a4;
    const float A1  = a8 * a2;
    const float A2  = A1 * A1, A4 = A2 * A2, A8 = A4 * A4;
    const float A16 = A8 * A8, A32 = A16 * A16, A64 = A32 * A32;
    float Al = 1.0f;
    if (lane & 1)  Al *= A1;
    if (lane & 2)  Al *= A2;
    if (lane & 4)  Al *= A4;
    if (lane & 8)  Al *= A8;
    if (lane & 16) Al *= A16;
    if (lane & 32) Al *= A32;

    const unsigned* PU = (const unsigned*)(Pall + ((size_t)b * F_FILT + f) * T_LEN);
    const int tile0 = chunk * TPC;
    const int itStart = (chunk == 0) ? 0 : -1;
    const unsigned P0 = 5u * (unsigned)tid;
    float carry = 0.f;

    unsigned sv[5];
    {
        const int tb = (tile0 + itStart) * 1600 + tid * 5;
#pragma unroll
        for (int q = 0; q < 5; ++q) sv[q] = PU[tb + q];
    }

    for (int it = itStart; it < TPC; ++it) {
        // unpack powers
        float p[RT];
#pragma unroll
        for (int q = 0; q < 5; ++q) {
            const h2_t hh = bch(sv[q]);
            p[2 * q]     = (float)hh.x;
            p[2 * q + 1] = (float)hh.y;
        }
        // prefetch next tile
        {
            const int nt = tile0 + it + 1;
            const int tb = (nt < CHUNKS * TPC ? nt : 0) * 1600 + tid * 5;
#pragma unroll
            for (int q = 0; q < 5; ++q) sv[q] = PU[tb + q];
        }

        float up[RT];
        float uu = 0.f;
#pragma unroll
        for (int r = 0; r < RT; ++r) {
            uu = fmaf(a, uu, sw * p[r]);
            up[r] = uu;
        }
        if (chunk == 0 && it == 0 && tid == 0) p0Lds = p[0];

        // ring tail (prev tile) read
        const bool doSlide = (it != itStart);
        unsigned tr = 0u;
        if (doSlide && tid < HALOP) tr = ringl[TILEP + tid];

        // intra-wave scan
        float v = uu;
        {
            float tv;
            tv = __shfl_up(v, 1);  if (lane >= 1)  v = fmaf(A1,  tv, v);
            tv = __shfl_up(v, 2);  if (lane >= 2)  v = fmaf(A2,  tv, v);
            tv = __shfl_up(v, 4);  if (lane >= 4)  v = fmaf(A4,  tv, v);
            tv = __shfl_up(v, 8);  if (lane >= 8)  v = fmaf(A8,  tv, v);
            tv = __shfl_up(v, 16); if (lane >= 16) v = fmaf(A16, tv, v);
            tv = __shfl_up(v, 32); if (lane >= 32) v = fmaf(A32, tv, v);
        }
        if (lane == 63) waveV[wave] = v;
        __syncthreads();                      // waveV + prev pooling done

        if (doSlide && tid < HALOP) ringl[tid] = tr;

        float cw, cc = (chunk == 0 && it == 0) ? p0Lds : carry;
#pragma unroll
        for (int ww = 0; ww < NWAVES; ++ww) {
            if (ww == wave) cw = cc;
            cc = fmaf(A64, cc, waveV[ww]);
        }
        carry = cc;
        float cin;
        {
            float ve = __shfl_up(v, 1);
            if (lane == 0) ve = 0.f;
            cin = fmaf(Al, cw, ve);
        }

        float apr = a;
#pragma unroll
        for (int j = 0; j < 5; ++j) {
            const float e0 = fmaf(apr, cin, up[2 * j]);     apr *= a;
            const float e1 = fmaf(apr, cin, up[2 * j + 1]); apr *= a;
            const float q0 = fmaf(p[2 * j],     fexp2(-alpha * flog2(EPS_PCENF + e0)), dlt);
            const float q1 = fmaf(p[2 * j + 1], fexp2(-alpha * flog2(EPS_PCENF + e1)), dlt);
            const float c0 = fexp2(inv_r * flog2(q0)) - dpow;
            const float c1 = fexp2(inv_r * flog2(q1)) - dpow;
            ringl[HALOP + P0 + j] = pk2(c0, c1);
        }
        __syncthreads();                      // ring complete

        if (it >= 0) {
            const int o = tid >> 4, l = tid & 15;
            float part = 0.f;
#pragma unroll
            for (int t = 0; t < 13; ++t) {
                const int kpp = l + 16 * t;
                part = fdot2(bch(ringl[o * 80 + kpp]), bch(pkpl[kpp]), part);
            }
            part += __shfl_xor(part, 1, 16);
            part += __shfl_xor(part, 2, 16);
            part += __shfl_xor(part, 4, 16);
            part += __shfl_xor(part, 8, 16);
            if (l == 0) pooled[it * NPT + o] += part;
        }
    }
    __syncthreads();

    const float bias = bias_g[f];
    for (int i = tid; i < NPOOL_BLK; i += THREADS)
        outp[((size_t)b * F_FILT + f) * 1000 + (size_t)(tile0 * NPT) + i] = pooled[i] + bias;
}

// ---------- instance norm over 1000 frames, in place ----------
__global__ __launch_bounds__(256) void leaf_norm(float* __restrict__ out)
{
    const int bf = blockIdx.x;
    float* p = out + (size_t)bf * 1000;
    __shared__ float buf[1000];
    __shared__ float red[4];
    const int tid = threadIdx.x;
    const int lane = tid & 63, wave = tid >> 6;

    float sum = 0.0f;
    for (int i = tid; i < 1000; i += 256) { float v = p[i]; buf[i] = v; sum += v; }
    for (int m = 1; m < 64; m <<= 1) sum += __shfl_xor(sum, m);
    if (lane == 0) red[wave] = sum;
    __syncthreads();
    const float mean = (red[0] + red[1] + red[2] + red[3]) * 0.001f;

    float vs = 0.0f;
    for (int i = tid; i < 1000; i += 256) { float d = buf[i] - mean; vs += d * d; }
    for (int m = 1; m < 64; m <<= 1) vs += __shfl_xor(vs, m);
    __syncthreads();
    if (lane == 0) red[wave] = vs;
    __syncthreads();
    const float var   = (red[0] + red[1] + red[2] + red[3]) * 0.001f;
    const float scale = rsqrtf(var + EPS_INF);
    for (int i = tid; i < 1000; i += 256) p[i] = (buf[i] - mean) * scale;
}

extern "C" void kernel_launch(void* const* d_in, const int* in_sizes, int n_in,
                              void* d_out, int out_size, void* d_ws, size_t ws_size,
                              hipStream_t stream)
{
    const float* x     = (const float*)d_in[0];
    const float* eta   = (const float*)d_in[1];
    const float* sigma = (const float*)d_in[2];
    const float* bw    = (const float*)d_in[3];
    const float* bias  = (const float*)d_in[4];
    const float* emaw  = (const float*)d_in[5];
    const float* alpha = (const float*)d_in[6];
    const float* delta = (const float*)d_in[7];
    const float* root  = (const float*)d_in[8];
    float* outp = (float*)d_out;

    _Float16* Atab  = (_Float16*)d_ws;                       // 133,120 B
    unsigned* pktab = (unsigned*)((char*)d_ws + 133120);     // 33,280 B
    _Float16* Pall  = (_Float16*)((char*)d_ws + 166400);     // 8*40*160000*2 = 102.4 MB

    hipLaunchKernelGGL(leaf_weights, dim3(NG), dim3(256), 0, stream,
                       eta, sigma, bw, Atab, pktab);
    hipLaunchKernelGGL(leaf_conv, dim3(B_BATCH * NG * NCH1), dim3(256), 0, stream,
                       x, sigma, Atab, Pall);
    hipLaunchKernelGGL(leaf_pcen, dim3(B_BATCH * F_FILT * CHUNKS), dim3(THREADS), 0, stream,
                       Pall, bias, emaw, alpha, delta, root, pktab, outp);
    hipLaunchKernelGGL(leaf_norm, dim3(B_BATCH * F_FILT), dim3(256), 0, stream, outp);
}

// Round 13
// 131.297 us; speedup vs baseline: 7.8931x; 1.1594x over previous
//
#include <hip/hip_runtime.h>
#include <math.h>

#define F_FILT   40
#define K_GABOR  401
#define HOP      160
#define T_LEN    160000
#define B_BATCH  8
#define EPS_PCENF 1e-6f
#define EPS_INF   1e-5f

// ---- kernel1 (MFMA conv) geometry ----
#define NG       5           // filter groups of 8
#define GF       8
#define NKMAX    13          // max K chunks of 32 taps (416)
#define TC       1280        // time samples per block (4 waves x 20 jtiles x 16)
#define UW       20          // j-tiles per wave
#define NCH1     125         // T_LEN / TC
#define OPOFF    852         // odd-phase pair array offset (u32)
#define XPAIRS   (OPOFF + 852)

// ---- kernel2 (PCEN) geometry ----
#define THREADS  320
#define NWAVES   5
#define RT       10
#define TILE     3200
#define TPC      10
#define CHUNKS   5
#define NPT      20
#define NPOOL_BLK 200
#define KP       208
#define HALOP    200
#define TILEP    1600
#define RINGP    1800

typedef _Float16 h2_t  __attribute__((ext_vector_type(2)));
typedef _Float16 half8 __attribute__((ext_vector_type(8)));
typedef float    f32x4 __attribute__((ext_vector_type(4)));

__device__ __forceinline__ float fdot2(h2_t a, h2_t b, float c) {
    return __builtin_amdgcn_fdot2(a, b, c, false);
}
__device__ __forceinline__ unsigned pk2(float a, float b) {
    return __builtin_bit_cast(unsigned, __builtin_amdgcn_cvt_pkrtz(a, b));
}
__device__ __forceinline__ h2_t bch(unsigned u) {
    return __builtin_bit_cast(h2_t, u);
}
// hardware transcendentals: v_exp_f32 (2^x), v_log_f32 (log2 x), ~1 ULP
__device__ __forceinline__ float fexp2(float x) { return __builtin_amdgcn_exp2f(x); }
__device__ __forceinline__ float flog2(float x) { return __builtin_amdgcn_logf(x); }

// group truncation params (shared formula: leaf_weights & k1)
__device__ __forceinline__ void group_span(float sigma0, int& klo, int& nk) {
    const int R = min(200, (int)ceilf(4.5f * sigma0));
    klo = (200 - R) & ~31;
    nk  = ((200 + R - klo) >> 5) + 1;
    if (nk > NKMAX) nk = NKMAX;
}

// ---------- setup: A-table (16 rows x 416 taps f16 per group) + pool kernel ----------
__global__ __launch_bounds__(256) void leaf_weights(
    const float* __restrict__ eta_g, const float* __restrict__ sigma_g,
    const float* __restrict__ bw_g,
    _Float16* __restrict__ Atab, unsigned* __restrict__ pktab)
{
    const int gi = blockIdx.x;
    const int f0 = gi * GF;
    int klo, nk;
    group_span(sigma_g[f0], klo, nk);

    // A: 52 chunks x 16 rows x 8 taps
    for (int idx = threadIdx.x; idx < 52 * 16 * 8; idx += 256) {
        const int c8 = idx >> 7;
        const int m  = (idx >> 3) & 15;
        const int i  = idx & 7;
        const int f  = f0 + (m >> 1);
        const int k  = klo + c8 * 8 + i;
        float w = 0.f;
        if (k <= 400) {
            const float sg = sigma_g[f];
            const float t  = (float)(k - 200);
            const float z  = t / sg;
            const float e  = (0.3989422804014327f / sg) * expf(-0.5f * z * z);
            const float ph = eta_g[f] * t;
            w = (m & 1) ? e * sinf(ph) : e * cosf(ph);
        }
        Atab[(size_t)(gi * 52 + c8) * 128 + m * 8 + i] = (_Float16)w;
    }
    // pool kernel for this group's 8 filters
    for (int idx = threadIdx.x; idx < GF * KP; idx += 256) {
        const int fl = idx / KP, i = idx % KP;
        const int f = f0 + fl;
        const float bw  = fminf(fmaxf(bw_g[f], 2.0f / 401.0f), 0.5f);
        const float den = bw * 0.5f * 400.0f;
        float pp[2];
        for (int j = 0; j < 2; ++j) {
            int k = 2 * i + j;
            float pv = 0.f;
            if (k < K_GABOR) {
                float tp = (float)(k - 201);
                float d = tp / den;
                pv = expf(-0.5f * d * d);
            }
            pp[j] = pv;
        }
        pktab[f * KP + i] = pk2(pp[0], pp[1]);
    }
}

__device__ __forceinline__ uint4 ld4(const unsigned* __restrict__ xp, int p) {
    uint4 v; v.x = xp[p]; v.y = xp[p + 1]; v.z = xp[p + 2]; v.w = xp[p + 3];
    return v;
}

// fully-unrolled k-loop with diagonal fragment reuse: B(jk+1,u) == B(jk,u+2)
template<int NK>
__device__ __forceinline__ void conv_kloop(
    const unsigned* __restrict__ xpair, const uint4* __restrict__ Ap,
    int aBase, int pB, f32x4* acc)
{
    uint4 F[UW];
#pragma unroll
    for (int u = 0; u < UW; ++u) F[u] = ld4(xpair, pB + 8 * u);
#pragma unroll
    for (int jk = 0; jk < NK; ++jk) {
        const half8 aCur = __builtin_bit_cast(half8, Ap[aBase + jk * 64]);
#pragma unroll
        for (int u = 0; u < UW; ++u) {
            acc[u] = __builtin_amdgcn_mfma_f32_16x16x32_f16(
                aCur, __builtin_bit_cast(half8, F[u]), acc[u], 0, 0, 0);
        }
        if (jk + 1 < NK) {
#pragma unroll
            for (int u = 0; u < UW - 2; ++u) F[u] = F[u + 2];   // renamed, no moves
            F[UW - 2] = ld4(xpair, pB + 16 * (jk + 1) + 8 * (UW - 2));
            F[UW - 1] = ld4(xpair, pB + 16 * (jk + 1) + 8 * (UW - 1));
        }
    }
}

// ---------- kernel1: MFMA Gabor conv -> power P[b][f][t] (f16), ALL batches ----------
__global__ __launch_bounds__(256) void leaf_conv(
    const float* __restrict__ x,
    const float* __restrict__ sigma_g,
    const _Float16* __restrict__ Atab,
    _Float16* __restrict__ Pall)           // [8][40][160000] f16
{
    __shared__ unsigned xpair[XPAIRS];     // even pairs [0,852), odd pairs [852,1704)

    const int gi = blockIdx.x % NG;
    const int ch = (blockIdx.x / NG) % NCH1;
    const int b  = blockIdx.x / (NG * NCH1);
    const int f0 = gi * GF;
    const int tid = threadIdx.x;
    const int lane = tid & 63;
    const int w    = tid >> 6;

    const float* __restrict__ xb = x + (size_t)b * T_LEN;
    _Float16* __restrict__ Pb = Pall + (size_t)b * F_FILT * T_LEN;

    int klo, nk;
    group_span(sigma_g[f0], klo, nk);
    // pad nk to template set {4,7,10,13}; extra chunks read zero-padded weights
    const int nkp = (nk <= 4) ? 4 : (nk <= 7) ? 7 : (nk <= 10) ? 10 : 13;
    const int t0   = ch * TC;
    const int base = t0 + klo - 400;

    // ---- stage x as two phase-shifted f16-pair copies ----
    if (tid < 213) {
        float v[9];
#pragma unroll
        for (int e = 0; e < 9; ++e) {
            const int gidx = base + 8 * tid + e;
            v[e] = (gidx >= 0 && gidx < T_LEN) ? xb[gidx] : 0.f;
        }
        uint4 pe, po;
        pe.x = pk2(v[0], v[1]); pe.y = pk2(v[2], v[3]);
        pe.z = pk2(v[4], v[5]); pe.w = pk2(v[6], v[7]);
        po.x = pk2(v[1], v[2]); po.y = pk2(v[3], v[4]);
        po.z = pk2(v[5], v[6]); po.w = pk2(v[7], v[8]);
        *(uint4*)&xpair[4 * tid]         = pe;
        *(uint4*)&xpair[OPOFF + 4 * tid] = po;
    }
    __syncthreads();

    // ---- k-loop: 20 j-tiles per wave, register-resident sliding fragments ----
    const int n  = lane & 15;
    const int kb = lane >> 4;
    const int q0 = ((n + 8 * kb) >> 1) + ((n & 1) ? OPOFF : 0);
    const int pB = q0 + 160 * w;           // + 8u + 16jk

    f32x4 acc[UW];
#pragma unroll
    for (int u = 0; u < UW; ++u) acc[u] = (f32x4){0.f, 0.f, 0.f, 0.f};

    const uint4* Ap = (const uint4*)Atab;
    const int aBase = (gi * 52 + kb) * 16 + n;   // c8 = 4jk + kb

    switch (nkp) {
        case 4:  conv_kloop<4>(xpair, Ap, aBase, pB, acc); break;
        case 7:  conv_kloop<7>(xpair, Ap, aBase, pB, acc); break;
        case 10: conv_kloop<10>(xpair, Ap, aBase, pB, acc); break;
        default: conv_kloop<13>(xpair, Ap, aBase, pB, acc); break;
    }

    // ---- epilogue: power, store P ----
    const int g  = lane >> 4;
    const int fA = f0 + 2 * g;
#pragma unroll
    for (int u = 0; u < UW; ++u) {
        const int t = t0 + (w * UW + u) * 16 + n;
        const float P0 = acc[u].x * acc[u].x + acc[u].y * acc[u].y;
        const float P1 = acc[u].z * acc[u].z + acc[u].w * acc[u].w;
        Pb[(size_t)fA * T_LEN + t]       = (_Float16)P0;
        Pb[(size_t)(fA + 1) * T_LEN + t] = (_Float16)P1;
    }
}

// ---------- kernel2: EMA + PCEN + pooling, ALL batches ----------
__global__ __launch_bounds__(THREADS) void leaf_pcen(
    const _Float16* __restrict__ Pall,
    const float* __restrict__ bias_g,
    const float* __restrict__ ema_g,
    const float* __restrict__ alpha_g,
    const float* __restrict__ delta_g,
    const float* __restrict__ root_g,
    const unsigned* __restrict__ pktab,
    float* __restrict__ outp)
{
    __shared__ unsigned ringl[RINGP];
    __shared__ unsigned pkpl[KP];
    __shared__ float pooled[NPOOL_BLK];
    __shared__ float waveV[NWAVES];
    __shared__ float p0Lds;

    const int f     = blockIdx.x % F_FILT;
    const int chunk = (blockIdx.x / F_FILT) % CHUNKS;
    const int b     = blockIdx.x / (F_FILT * CHUNKS);
    const int tid  = threadIdx.x;
    const int lane = tid & 63;
    const int wave = tid >> 6;

    const float sw    = fminf(fmaxf(ema_g[f], 0.0f), 1.0f);
    const float a     = 1.0f - sw;
    const float alpha = fminf(alpha_g[f], 1.0f);
    const float inv_r = 1.0f / fmaxf(root_g[f], 1.0f);
    const float dlt   = delta_g[f];
    const float dpow  = fexp2(inv_r * flog2(dlt));
    const bool  rt1   = (inv_r == 1.0f);   // uniform: (q+d)^1 - d^1 == p*denp

    for (int i = tid; i < RINGP; i += THREADS) ringl[i] = 0u;
    for (int i = tid; i < NPOOL_BLK; i += THREADS) pooled[i] = 0.f;
    if (tid < KP) pkpl[tid] = pktab[f * KP + tid];

    const float a2 = a * a, a4 = a2 * a2, a8 = a4 * a4;
    const float A1  = a8 * a2;
    const float A2  = A1 * A1, A4 = A2 * A2, A8 = A4 * A4;
    const float A16 = A8 * A8, A32 = A16 * A16, A64 = A32 * A32;
    float Al = 1.0f;
    if (lane & 1)  Al *= A1;
    if (lane & 2)  Al *= A2;
    if (lane & 4)  Al *= A4;
    if (lane & 8)  Al *= A8;
    if (lane & 16) Al *= A16;
    if (lane & 32) Al *= A32;

    const unsigned* PU = (const unsigned*)(Pall + ((size_t)b * F_FILT + f) * T_LEN);
    const int tile0 = chunk * TPC;
    const int itStart = (chunk == 0) ? 0 : -1;
    const unsigned P0 = 5u * (unsigned)tid;
    float carry = 0.f;

    unsigned sv[5];
    {
        const int tb = (tile0 + itStart) * 1600 + tid * 5;
#pragma unroll
        for (int q = 0; q < 5; ++q) sv[q] = PU[tb + q];
    }

    for (int it = itStart; it < TPC; ++it) {
        // unpack powers
        float p[RT];
#pragma unroll
        for (int q = 0; q < 5; ++q) {
            const h2_t hh = bch(sv[q]);
            p[2 * q]     = (float)hh.x;
            p[2 * q + 1] = (float)hh.y;
        }
        // prefetch next tile
        {
            const int nt = tile0 + it + 1;
            const int tb = (nt < CHUNKS * TPC ? nt : 0) * 1600 + tid * 5;
#pragma unroll
            for (int q = 0; q < 5; ++q) sv[q] = PU[tb + q];
        }

        float up[RT];
        float uu = 0.f;
#pragma unroll
        for (int r = 0; r < RT; ++r) {
            uu = fmaf(a, uu, sw * p[r]);
            up[r] = uu;
        }
        if (chunk == 0 && it == 0 && tid == 0) p0Lds = p[0];

        // ring tail (prev tile) read
        const bool doSlide = (it != itStart);
        unsigned tr = 0u;
        if (doSlide && tid < HALOP) tr = ringl[TILEP + tid];

        // intra-wave scan
        float v = uu;
        {
            float tv;
            tv = __shfl_up(v, 1);  if (lane >= 1)  v = fmaf(A1,  tv, v);
            tv = __shfl_up(v, 2);  if (lane >= 2)  v = fmaf(A2,  tv, v);
            tv = __shfl_up(v, 4);  if (lane >= 4)  v = fmaf(A4,  tv, v);
            tv = __shfl_up(v, 8);  if (lane >= 8)  v = fmaf(A8,  tv, v);
            tv = __shfl_up(v, 16); if (lane >= 16) v = fmaf(A16, tv, v);
            tv = __shfl_up(v, 32); if (lane >= 32) v = fmaf(A32, tv, v);
        }
        if (lane == 63) waveV[wave] = v;
        __syncthreads();                      // waveV + prev pooling done

        if (doSlide && tid < HALOP) ringl[tid] = tr;

        float cw, cc = (chunk == 0 && it == 0) ? p0Lds : carry;
#pragma unroll
        for (int ww = 0; ww < NWAVES; ++ww) {
            if (ww == wave) cw = cc;
            cc = fmaf(A64, cc, waveV[ww]);
        }
        carry = cc;
        float cin;
        {
            float ve = __shfl_up(v, 1);
            if (lane == 0) ve = 0.f;
            cin = fmaf(Al, cw, ve);
        }

        float apr = a;
#pragma unroll
        for (int j = 0; j < 5; ++j) {
            const float e0 = fmaf(apr, cin, up[2 * j]);     apr *= a;
            const float e1 = fmaf(apr, cin, up[2 * j + 1]); apr *= a;
            const float d0 = fexp2(-alpha * flog2(EPS_PCENF + e0));
            const float d1 = fexp2(-alpha * flog2(EPS_PCENF + e1));
            float c0, c1;
            if (rt1) {
                c0 = p[2 * j] * d0;
                c1 = p[2 * j + 1] * d1;
            } else {
                const float q0 = fmaf(p[2 * j],     d0, dlt);
                const float q1 = fmaf(p[2 * j + 1], d1, dlt);
                c0 = fexp2(inv_r * flog2(q0)) - dpow;
                c1 = fexp2(inv_r * flog2(q1)) - dpow;
            }
            ringl[HALOP + P0 + j] = pk2(c0, c1);
        }
        __syncthreads();                      // ring complete

        if (it >= 0) {
            const int o = tid >> 4, l = tid & 15;
            float part = 0.f;
#pragma unroll
            for (int t = 0; t < 13; ++t) {
                const int kpp = l + 16 * t;
                part = fdot2(bch(ringl[o * 80 + kpp]), bch(pkpl[kpp]), part);
            }
            part += __shfl_xor(part, 1, 16);
            part += __shfl_xor(part, 2, 16);
            part += __shfl_xor(part, 4, 16);
            part += __shfl_xor(part, 8, 16);
            if (l == 0) pooled[it * NPT + o] += part;
        }
    }
    __syncthreads();

    const float bias = bias_g[f];
    for (int i = tid; i < NPOOL_BLK; i += THREADS)
        outp[((size_t)b * F_FILT + f) * 1000 + (size_t)(tile0 * NPT) + i] = pooled[i] + bias;
}

// ---------- instance norm over 1000 frames, in place ----------
__global__ __launch_bounds__(256) void leaf_norm(float* __restrict__ out)
{
    const int bf = blockIdx.x;
    float* p = out + (size_t)bf * 1000;
    __shared__ float buf[1000];
    __shared__ float red[4];
    const int tid = threadIdx.x;
    const int lane = tid & 63, wave = tid >> 6;

    float sum = 0.0f;
    for (int i = tid; i < 1000; i += 256) { float v = p[i]; buf[i] = v; sum += v; }
    for (int m = 1; m < 64; m <<= 1) sum += __shfl_xor(sum, m);
    if (lane == 0) red[wave] = sum;
    __syncthreads();
    const float mean = (red[0] + red[1] + red[2] + red[3]) * 0.001f;

    float vs = 0.0f;
    for (int i = tid; i < 1000; i += 256) { float d = buf[i] - mean; vs += d * d; }
    for (int m = 1; m < 64; m <<= 1) vs += __shfl_xor(vs, m);
    __syncthreads();
    if (lane == 0) red[wave] = vs;
    __syncthreads();
    const float var   = (red[0] + red[1] + red[2] + red[3]) * 0.001f;
    const float scale = rsqrtf(var + EPS_INF);
    for (int i = tid; i < 1000; i += 256) p[i] = (buf[i] - mean) * scale;
}

extern "C" void kernel_launch(void* const* d_in, const int* in_sizes, int n_in,
                              void* d_out, int out_size, void* d_ws, size_t ws_size,
                              hipStream_t stream)
{
    const float* x     = (const float*)d_in[0];
    const float* eta   = (const float*)d_in[1];
    const float* sigma = (const float*)d_in[2];
    const float* bw    = (const float*)d_in[3];
    const float* bias  = (const float*)d_in[4];
    const float* emaw  = (const float*)d_in[5];
    const float* alpha = (const float*)d_in[6];
    const float* delta = (const float*)d_in[7];
    const float* root  = (const float*)d_in[8];
    float* outp = (float*)d_out;

    _Float16* Atab  = (_Float16*)d_ws;                       // 133,120 B
    unsigned* pktab = (unsigned*)((char*)d_ws + 133120);     // 33,280 B
    _Float16* Pall  = (_Float16*)((char*)d_ws + 166400);     // 8*40*160000*2 = 102.4 MB

    hipLaunchKernelGGL(leaf_weights, dim3(NG), dim3(256), 0, stream,
                       eta, sigma, bw, Atab, pktab);
    hipLaunchKernelGGL(leaf_conv, dim3(B_BATCH * NG * NCH1), dim3(256), 0, stream,
                       x, sigma, Atab, Pall);
    hipLaunchKernelGGL(leaf_pcen, dim3(B_BATCH * F_FILT * CHUNKS), dim3(THREADS), 0, stream,
                       Pall, bias, emaw, alpha, delta, root, pktab, outp);
    hipLaunchKernelGGL(leaf_norm, dim3(B_BATCH * F_FILT), dim3(256), 0, stream, outp);
}

// Round 14
// 124.964 us; speedup vs baseline: 8.2931x; 1.0507x over previous
//
#include <hip/hip_runtime.h>
#include <math.h>

#define F_FILT   40
#define K_GABOR  401
#define HOP      160
#define T_LEN    160000
#define B_BATCH  8
#define EPS_PCENF 1e-6f
#define EPS_INF   1e-5f

// ---- kernel1 (MFMA conv) geometry ----
#define NG       5           // filter groups of 8
#define GF       8
#define NKMAX    13          // max K chunks of 32 taps (416)
#define TC       640         // time samples per block (4 waves x 10 jtiles x 16)
#define UW       10          // j-tiles per wave
#define NCH1     250         // T_LEN / TC
#define OPOFF    544         // odd-phase pair array offset (u32)
#define XPAIRS   (OPOFF + 544)
#define NSTG     136         // staging threads (136*8 = 1088 samples)

// ---- kernel2 (PCEN) geometry ----
#define THREADS  320
#define NWAVES   5
#define RT       10
#define TILE     3200
#define TPC      10
#define CHUNKS   5
#define NPT      20
#define NPOOL_BLK 200
#define KP       208
#define HALOP    200
#define TILEP    1600
#define RINGP    1800

typedef _Float16 h2_t  __attribute__((ext_vector_type(2)));
typedef _Float16 half8 __attribute__((ext_vector_type(8)));
typedef float    f32x4 __attribute__((ext_vector_type(4)));

__device__ __forceinline__ float fdot2(h2_t a, h2_t b, float c) {
    return __builtin_amdgcn_fdot2(a, b, c, false);
}
__device__ __forceinline__ unsigned pk2(float a, float b) {
    return __builtin_bit_cast(unsigned, __builtin_amdgcn_cvt_pkrtz(a, b));
}
__device__ __forceinline__ h2_t bch(unsigned u) {
    return __builtin_bit_cast(h2_t, u);
}
// hardware transcendentals: v_exp_f32 (2^x), v_log_f32 (log2 x), ~1 ULP
__device__ __forceinline__ float fexp2(float x) { return __builtin_amdgcn_exp2f(x); }
__device__ __forceinline__ float flog2(float x) { return __builtin_amdgcn_logf(x); }

// group truncation params (shared formula: leaf_weights & k1)
__device__ __forceinline__ void group_span(float sigma0, int& klo, int& nk) {
    const int R = min(200, (int)ceilf(4.5f * sigma0));
    klo = (200 - R) & ~31;
    nk  = ((200 + R - klo) >> 5) + 1;
    if (nk > NKMAX) nk = NKMAX;
}

// ---------- setup: A-table (16 rows x 416 taps f16 per group) + pool kernel ----------
__global__ __launch_bounds__(256) void leaf_weights(
    const float* __restrict__ eta_g, const float* __restrict__ sigma_g,
    const float* __restrict__ bw_g,
    _Float16* __restrict__ Atab, unsigned* __restrict__ pktab)
{
    const int gi = blockIdx.x;
    const int f0 = gi * GF;
    int klo, nk;
    group_span(sigma_g[f0], klo, nk);

    // A: 52 chunks x 16 rows x 8 taps
    for (int idx = threadIdx.x; idx < 52 * 16 * 8; idx += 256) {
        const int c8 = idx >> 7;
        const int m  = (idx >> 3) & 15;
        const int i  = idx & 7;
        const int f  = f0 + (m >> 1);
        const int k  = klo + c8 * 8 + i;
        float w = 0.f;
        if (k <= 400) {
            const float sg = sigma_g[f];
            const float t  = (float)(k - 200);
            const float z  = t / sg;
            const float e  = (0.3989422804014327f / sg) * expf(-0.5f * z * z);
            const float ph = eta_g[f] * t;
            w = (m & 1) ? e * sinf(ph) : e * cosf(ph);
        }
        Atab[(size_t)(gi * 52 + c8) * 128 + m * 8 + i] = (_Float16)w;
    }
    // pool kernel for this group's 8 filters
    for (int idx = threadIdx.x; idx < GF * KP; idx += 256) {
        const int fl = idx / KP, i = idx % KP;
        const int f = f0 + fl;
        const float bw  = fminf(fmaxf(bw_g[f], 2.0f / 401.0f), 0.5f);
        const float den = bw * 0.5f * 400.0f;
        float pp[2];
        for (int j = 0; j < 2; ++j) {
            int k = 2 * i + j;
            float pv = 0.f;
            if (k < K_GABOR) {
                float tp = (float)(k - 201);
                float d = tp / den;
                pv = expf(-0.5f * d * d);
            }
            pp[j] = pv;
        }
        pktab[f * KP + i] = pk2(pp[0], pp[1]);
    }
}

__device__ __forceinline__ uint4 ld4(const unsigned* __restrict__ xp, int p) {
    uint4 v; v.x = xp[p]; v.y = xp[p + 1]; v.z = xp[p + 2]; v.w = xp[p + 3];
    return v;
}

// fully-unrolled k-loop with diagonal fragment reuse: B(jk+1,u) == B(jk,u+2)
template<int NK>
__device__ __forceinline__ void conv_kloop(
    const unsigned* __restrict__ xpair, const uint4* __restrict__ Ap,
    int aBase, int pB, f32x4* acc)
{
    uint4 F[UW];
#pragma unroll
    for (int u = 0; u < UW; ++u) F[u] = ld4(xpair, pB + 8 * u);
#pragma unroll
    for (int jk = 0; jk < NK; ++jk) {
        const half8 aCur = __builtin_bit_cast(half8, Ap[aBase + jk * 64]);
#pragma unroll
        for (int u = 0; u < UW; ++u) {
            acc[u] = __builtin_amdgcn_mfma_f32_16x16x32_f16(
                aCur, __builtin_bit_cast(half8, F[u]), acc[u], 0, 0, 0);
        }
        if (jk + 1 < NK) {
#pragma unroll
            for (int u = 0; u < UW - 2; ++u) F[u] = F[u + 2];   // renamed, no moves
            F[UW - 2] = ld4(xpair, pB + 16 * (jk + 1) + 8 * (UW - 2));
            F[UW - 1] = ld4(xpair, pB + 16 * (jk + 1) + 8 * (UW - 1));
        }
    }
}

// ---------- kernel1: MFMA Gabor conv -> power P[b][f][t] (f16), ALL batches ----------
__global__ __launch_bounds__(256) void leaf_conv(
    const float* __restrict__ x,
    const float* __restrict__ sigma_g,
    const _Float16* __restrict__ Atab,
    _Float16* __restrict__ Pall)           // [8][40][160000] f16
{
    __shared__ unsigned xpair[XPAIRS];     // even pairs [0,544), odd pairs [544,1088)

    const int gi = blockIdx.x % NG;
    const int ch = (blockIdx.x / NG) % NCH1;
    const int b  = blockIdx.x / (NG * NCH1);
    const int f0 = gi * GF;
    const int tid = threadIdx.x;
    const int lane = tid & 63;
    const int w    = tid >> 6;

    const float* __restrict__ xb = x + (size_t)b * T_LEN;
    _Float16* __restrict__ Pb = Pall + (size_t)b * F_FILT * T_LEN;

    int klo, nk;
    group_span(sigma_g[f0], klo, nk);
    // pad nk to template set {4,7,10,13}; extra chunks read zero-padded weights
    const int nkp = (nk <= 4) ? 4 : (nk <= 7) ? 7 : (nk <= 10) ? 10 : 13;
    const int t0   = ch * TC;
    const int base = t0 + klo - 400;

    // ---- stage x as two phase-shifted f16-pair copies ----
    if (tid < NSTG) {
        float v[9];
#pragma unroll
        for (int e = 0; e < 9; ++e) {
            const int gidx = base + 8 * tid + e;
            v[e] = (gidx >= 0 && gidx < T_LEN) ? xb[gidx] : 0.f;
        }
        uint4 pe, po;
        pe.x = pk2(v[0], v[1]); pe.y = pk2(v[2], v[3]);
        pe.z = pk2(v[4], v[5]); pe.w = pk2(v[6], v[7]);
        po.x = pk2(v[1], v[2]); po.y = pk2(v[3], v[4]);
        po.z = pk2(v[5], v[6]); po.w = pk2(v[7], v[8]);
        *(uint4*)&xpair[4 * tid]         = pe;
        *(uint4*)&xpair[OPOFF + 4 * tid] = po;
    }
    __syncthreads();

    // ---- k-loop: 10 j-tiles per wave, register-resident sliding fragments ----
    const int n  = lane & 15;
    const int kb = lane >> 4;
    const int q0 = ((n + 8 * kb) >> 1) + ((n & 1) ? OPOFF : 0);
    const int pB = q0 + 80 * w;            // + 8u + 16jk

    f32x4 acc[UW];
#pragma unroll
    for (int u = 0; u < UW; ++u) acc[u] = (f32x4){0.f, 0.f, 0.f, 0.f};

    const uint4* Ap = (const uint4*)Atab;
    const int aBase = (gi * 52 + kb) * 16 + n;   // c8 = 4jk + kb

    switch (nkp) {
        case 4:  conv_kloop<4>(xpair, Ap, aBase, pB, acc); break;
        case 7:  conv_kloop<7>(xpair, Ap, aBase, pB, acc); break;
        case 10: conv_kloop<10>(xpair, Ap, aBase, pB, acc); break;
        default: conv_kloop<13>(xpair, Ap, aBase, pB, acc); break;
    }

    // ---- epilogue: power, store P ----
    const int g  = lane >> 4;
    const int fA = f0 + 2 * g;
#pragma unroll
    for (int u = 0; u < UW; ++u) {
        const int t = t0 + (w * UW + u) * 16 + n;
        const float P0 = acc[u].x * acc[u].x + acc[u].y * acc[u].y;
        const float P1 = acc[u].z * acc[u].z + acc[u].w * acc[u].w;
        Pb[(size_t)fA * T_LEN + t]       = (_Float16)P0;
        Pb[(size_t)(fA + 1) * T_LEN + t] = (_Float16)P1;
    }
}

// ---------- kernel2: EMA + PCEN + pooling, ALL batches ----------
__global__ __launch_bounds__(THREADS) void leaf_pcen(
    const _Float16* __restrict__ Pall,
    const float* __restrict__ bias_g,
    const float* __restrict__ ema_g,
    const float* __restrict__ alpha_g,
    const float* __restrict__ delta_g,
    const float* __restrict__ root_g,
    const unsigned* __restrict__ pktab,
    float* __restrict__ outp)
{
    __shared__ unsigned ringl[RINGP];
    __shared__ unsigned pkpl[KP];
    __shared__ float pooled[NPOOL_BLK];
    __shared__ float waveV[NWAVES];
    __shared__ float p0Lds;

    const int f     = blockIdx.x % F_FILT;
    const int chunk = (blockIdx.x / F_FILT) % CHUNKS;
    const int b     = blockIdx.x / (F_FILT * CHUNKS);
    const int tid  = threadIdx.x;
    const int lane = tid & 63;
    const int wave = tid >> 6;

    const float sw    = fminf(fmaxf(ema_g[f], 0.0f), 1.0f);
    const float a     = 1.0f - sw;
    const float alpha = fminf(alpha_g[f], 1.0f);
    const float inv_r = 1.0f / fmaxf(root_g[f], 1.0f);
    const float dlt   = delta_g[f];
    const float dpow  = fexp2(inv_r * flog2(dlt));
    const bool  rt1   = (inv_r == 1.0f);   // uniform: (q+d)^1 - d^1 == p*denp

    for (int i = tid; i < RINGP; i += THREADS) ringl[i] = 0u;
    for (int i = tid; i < NPOOL_BLK; i += THREADS) pooled[i] = 0.f;
    if (tid < KP) pkpl[tid] = pktab[f * KP + tid];

    const float a2 = a * a, a4 = a2 * a2, a8 = a4 * a4;
    const float A1  = a8 * a2;
    const float A2  = A1 * A1, A4 = A2 * A2, A8 = A4 * A4;
    const float A16 = A8 * A8, A32 = A16 * A16, A64 = A32 * A32;
    float Al = 1.0f;
    if (lane & 1)  Al *= A1;
    if (lane & 2)  Al *= A2;
    if (lane & 4)  Al *= A4;
    if (lane & 8)  Al *= A8;
    if (lane & 16) Al *= A16;
    if (lane & 32) Al *= A32;

    const unsigned* PU = (const unsigned*)(Pall + ((size_t)b * F_FILT + f) * T_LEN);
    const int tile0 = chunk * TPC;
    const int itStart = (chunk == 0) ? 0 : -1;
    const unsigned P0 = 5u * (unsigned)tid;
    float carry = 0.f;

    unsigned sv[5];
    {
        const int tb = (tile0 + itStart) * 1600 + tid * 5;
#pragma unroll
        for (int q = 0; q < 5; ++q) sv[q] = PU[tb + q];
    }

    for (int it = itStart; it < TPC; ++it) {
        // unpack powers
        float p[RT];
#pragma unroll
        for (int q = 0; q < 5; ++q) {
            const h2_t hh = bch(sv[q]);
            p[2 * q]     = (float)hh.x;
            p[2 * q + 1] = (float)hh.y;
        }
        // prefetch next tile
        {
            const int nt = tile0 + it + 1;
            const int tb = (nt < CHUNKS * TPC ? nt : 0) * 1600 + tid * 5;
#pragma unroll
            for (int q = 0; q < 5; ++q) sv[q] = PU[tb + q];
        }

        float up[RT];
        float uu = 0.f;
#pragma unroll
        for (int r = 0; r < RT; ++r) {
            uu = fmaf(a, uu, sw * p[r]);
            up[r] = uu;
        }
        if (chunk == 0 && it == 0 && tid == 0) p0Lds = p[0];

        // ring tail (prev tile) read
        const bool doSlide = (it != itStart);
        unsigned tr = 0u;
        if (doSlide && tid < HALOP) tr = ringl[TILEP + tid];

        // intra-wave scan
        float v = uu;
        {
            float tv;
            tv = __shfl_up(v, 1);  if (lane >= 1)  v = fmaf(A1,  tv, v);
            tv = __shfl_up(v, 2);  if (lane >= 2)  v = fmaf(A2,  tv, v);
            tv = __shfl_up(v, 4);  if (lane >= 4)  v = fmaf(A4,  tv, v);
            tv = __shfl_up(v, 8);  if (lane >= 8)  v = fmaf(A8,  tv, v);
            tv = __shfl_up(v, 16); if (lane >= 16) v = fmaf(A16, tv, v);
            tv = __shfl_up(v, 32); if (lane >= 32) v = fmaf(A32, tv, v);
        }
        if (lane == 63) waveV[wave] = v;
        __syncthreads();                      // waveV + prev pooling done

        if (doSlide && tid < HALOP) ringl[tid] = tr;

        float cw, cc = (chunk == 0 && it == 0) ? p0Lds : carry;
#pragma unroll
        for (int ww = 0; ww < NWAVES; ++ww) {
            if (ww == wave) cw = cc;
            cc = fmaf(A64, cc, waveV[ww]);
        }
        carry = cc;
        float cin;
        {
            float ve = __shfl_up(v, 1);
            if (lane == 0) ve = 0.f;
            cin = fmaf(Al, cw, ve);
        }

        float apr = a;
#pragma unroll
        for (int j = 0; j < 5; ++j) {
            const float e0 = fmaf(apr, cin, up[2 * j]);     apr *= a;
            const float e1 = fmaf(apr, cin, up[2 * j + 1]); apr *= a;
            const float d0 = fexp2(-alpha * flog2(EPS_PCENF + e0));
            const float d1 = fexp2(-alpha * flog2(EPS_PCENF + e1));
            float c0, c1;
            if (rt1) {
                c0 = p[2 * j] * d0;
                c1 = p[2 * j + 1] * d1;
            } else {
                const float q0 = fmaf(p[2 * j],     d0, dlt);
                const float q1 = fmaf(p[2 * j + 1], d1, dlt);
                c0 = fexp2(inv_r * flog2(q0)) - dpow;
                c1 = fexp2(inv_r * flog2(q1)) - dpow;
            }
            ringl[HALOP + P0 + j] = pk2(c0, c1);
        }
        __syncthreads();                      // ring complete

        if (it >= 0) {
            const int o = tid >> 4, l = tid & 15;
            float part = 0.f;
#pragma unroll
            for (int t = 0; t < 13; ++t) {
                const int kpp = l + 16 * t;
                part = fdot2(bch(ringl[o * 80 + kpp]), bch(pkpl[kpp]), part);
            }
            part += __shfl_xor(part, 1, 16);
            part += __shfl_xor(part, 2, 16);
            part += __shfl_xor(part, 4, 16);
            part += __shfl_xor(part, 8, 16);
            if (l == 0) pooled[it * NPT + o] += part;
        }
    }
    __syncthreads();

    const float bias = bias_g[f];
    for (int i = tid; i < NPOOL_BLK; i += THREADS)
        outp[((size_t)b * F_FILT + f) * 1000 + (size_t)(tile0 * NPT) + i] = pooled[i] + bias;
}

// ---------- instance norm over 1000 frames, in place ----------
__global__ __launch_bounds__(256) void leaf_norm(float* __restrict__ out)
{
    const int bf = blockIdx.x;
    float* p = out + (size_t)bf * 1000;
    __shared__ float buf[1000];
    __shared__ float red[4];
    const int tid = threadIdx.x;
    const int lane = tid & 63, wave = tid >> 6;

    float sum = 0.0f;
    for (int i = tid; i < 1000; i += 256) { float v = p[i]; buf[i] = v; sum += v; }
    for (int m = 1; m < 64; m <<= 1) sum += __shfl_xor(sum, m);
    if (lane == 0) red[wave] = sum;
    __syncthreads();
    const float mean = (red[0] + red[1] + red[2] + red[3]) * 0.001f;

    float vs = 0.0f;
    for (int i = tid; i < 1000; i += 256) { float d = buf[i] - mean; vs += d * d; }
    for (int m = 1; m < 64; m <<= 1) vs += __shfl_xor(vs, m);
    __syncthreads();
    if (lane == 0) red[wave] = vs;
    __syncthreads();
    const float var   = (red[0] + red[1] + red[2] + red[3]) * 0.001f;
    const float scale = rsqrtf(var + EPS_INF);
    for (int i = tid; i < 1000; i += 256) p[i] = (buf[i] - mean) * scale;
}

extern "C" void kernel_launch(void* const* d_in, const int* in_sizes, int n_in,
                              void* d_out, int out_size, void* d_ws, size_t ws_size,
                              hipStream_t stream)
{
    const float* x     = (const float*)d_in[0];
    const float* eta   = (const float*)d_in[1];
    const float* sigma = (const float*)d_in[2];
    const float* bw    = (const float*)d_in[3];
    const float* bias  = (const float*)d_in[4];
    const float* emaw  = (const float*)d_in[5];
    const float* alpha = (const float*)d_in[6];
    const float* delta = (const float*)d_in[7];
    const float* root  = (const float*)d_in[8];
    float* outp = (float*)d_out;

    _Float16* Atab  = (_Float16*)d_ws;                       // 133,120 B
    unsigned* pktab = (unsigned*)((char*)d_ws + 133120);     // 33,280 B
    _Float16* Pall  = (_Float16*)((char*)d_ws + 166400);     // 8*40*160000*2 = 102.4 MB

    hipLaunchKernelGGL(leaf_weights, dim3(NG), dim3(256), 0, stream,
                       eta, sigma, bw, Atab, pktab);
    hipLaunchKernelGGL(leaf_conv, dim3(B_BATCH * NG * NCH1), dim3(256), 0, stream,
                       x, sigma, Atab, Pall);
    hipLaunchKernelGGL(leaf_pcen, dim3(B_BATCH * F_FILT * CHUNKS), dim3(THREADS), 0, stream,
                       Pall, bias, emaw, alpha, delta, root, pktab, outp);
    hipLaunchKernelGGL(leaf_norm, dim3(B_BATCH * F_FILT), dim3(256), 0, stream, outp);
}